// Round 5
// baseline (516.037 us; speedup 1.0000x reference)
//
#include <hip/hip_runtime.h>

// HiPPO-LegS scan — round 11: mscan -> per-wave barrier-free serial scan.
//  * Round-10 mscan (32 blocks, 15 serial chain_step_b16, 2 barriers/step,
//    133 µs @ 1.7% occupancy) decomposes: B operand is global (chunk set A,
//    launch-known) and each wave touches only its own 16 P-rows -> zero
//    cross-wave dataflow. New mscan_w: 160 blocks x 64 thr (one wave per
//    (g, h, m-tile)), private 8.7 KB LDS P-tile, NO barriers, per-nt
//    double-buffered B loads + cross-step prefetch of next node's first
//    B-tile (hidden under writeback/copyout/reload).
//  * k1 / gscan / k3h unchanged from round 10.
// Pipeline: k1(512) -> mscan_w(160) -> gscan(32) -> k3h(512). 4 launches.

#define LDK 136  // f16 k-stride of LDS state rows

using f16 = _Float16;
typedef __attribute__((ext_vector_type(8))) f16 f16x8;
typedef __attribute__((ext_vector_type(4))) float f32x4;

__device__ __forceinline__ f32x4 mfma3(f16x8 ah, f16x8 al, f16x8 bh, f16x8 bl,
                                       f32x4 c) {
  c = __builtin_amdgcn_mfma_f32_16x16x32_f16(ah, bh, c, 0, 0, 0);
  c = __builtin_amdgcn_mfma_f32_16x16x32_f16(ah, bl, c, 0, 0, 0);
  c = __builtin_amdgcn_mfma_f32_16x16x32_f16(al, bh, c, 0, 0, 0);
  return c;
}

__device__ __forceinline__ void split8(const float* v, f16x8& h, f16x8& l) {
#pragma unroll
  for (int j = 0; j < 8; ++j) {
    const float x = v[j];
    const f16 hh = (f16)x;
    h[j] = hh;
    l[j] = (f16)(x - (float)hh);
  }
}

// global m-tile owned by (h, slot): h=0 -> {0,7,1,6}, h=1 -> {2,5,3,4}
__device__ __forceinline__ int slot2mt(int h, int slot) {
  if (h == 0) return (slot & 1) ? 7 - (slot >> 1) : (slot >> 1);
  return (slot & 1) ? 5 - (slot >> 1) : 2 + (slot >> 1);
}

// ---------------------------------------------------------------------------
// Staged-A layout (f32, LDS, 9216 floats = 36 KB): triangular slice rows>=32,
// packed per k-tile: kt0 rows 32..127, kt1 rows 32..127, kt2 rows 64..127,
// kt3 rows 96..127; each row-slice = 32 f32 = 8 chunks of 16B.
// Swizzle: within a row, chunk c holds global chunk (c ^ (rp&7)).

__device__ __forceinline__ void gload_lds16(const float* g, float* l) {
  __builtin_amdgcn_global_load_lds(
      (const __attribute__((address_space(1))) unsigned int*)g,
      (__attribute__((address_space(3))) unsigned int*)l, 16, 0, 0);
}

// per-thread step-invariant source offsets (f32 units into A_l)
__device__ __forceinline__ void compute_soff(int tid, int (&soff)[8]) {
#pragma unroll
  for (int it = 0; it < 8; ++it) {
    const int m = tid + it * 320;  // LDS chunk index
    if (m < 2304) {
      const int kt = (m >= 768) + (m >= 1536) + (m >= 2048);
      const int local = m - ((kt >= 1) * 768 + (kt >= 2) * 768 + (kt >= 3) * 512);
      const int rp = local >> 3, c = local & 7;
      const int r = rp + 32 + (kt >= 2) * 32 + (kt >= 3) * 32;
      soff[it] = r * 128 + kt * 32 + ((c ^ (rp & 7)) << 2);
    } else {
      soff[it] = 0;
    }
  }
}

__device__ __forceinline__ void issue_A(const float* __restrict__ Al,
                                        float* __restrict__ Ast,
                                        const int (&soff)[8], int tid) {
#pragma unroll
  for (int it = 0; it < 8; ++it) {
    if (it < 7 || tid < 64)  // 2304 = 7*320 + 64 (wave 0 only on last iter)
      gload_lds16(Al + soff[it], Ast + (tid + it * 320) * 4);
  }
}

// staged B-fragment read (nt>=2): two swizzled 16B LDS reads + split
__device__ __forceinline__ void read_staged(const float* __restrict__ Ast,
                                            int nt, int kt, int lr, int q,
                                            f16x8& ch, f16x8& cl) {
  const int rp = nt * 16 + lr - (32 + (kt >= 2) * 32 + (kt >= 3) * 32);
  const float* pb =
      Ast + ((kt >= 1) * 3072 + (kt >= 2) * 3072 + (kt >= 3) * 2048) + rp * 32;
  float raw[8];
  *(float4*)&raw[0] = *(const float4*)(pb + (((2 * q + 0) ^ (rp & 7)) << 2));
  *(float4*)&raw[4] = *(const float4*)(pb + (((2 * q + 1) ^ (rp & 7)) << 2));
  split8(raw, ch, cl);
}

// ---------------------------------------------------------------------------
// chain_step_k1: B operand from staged LDS (nt>=2) + direct regs (nt<2).
// Issues next step's A staging between the two barriers. EXTRA==1 semantics.
__device__ __forceinline__ void chain_step_k1(const float* __restrict__ Acur,
                                              const float* __restrict__ Anext,
                                              const float* __restrict__ x32,
                                              const float* __restrict__ Bvl,
                                              f16* __restrict__ Ph,
                                              f16* __restrict__ Pl,
                                              float* __restrict__ Ast,
                                              const int (&soff)[8],
                                              int wv, int mt) {
  const int tid = threadIdx.x;
  const int lane = tid & 63, lr = lane & 15, q = lane >> 4;
  const bool wrow = (mt >= 8);
  const int ktA0 = wrow ? 0 : (mt >> 1);
  f16x8 ah[4], al[4];
#pragma unroll
  for (int kt = 0; kt < 4; ++kt) {
    if (kt >= ktA0) {
      const int off = (wv * 16 + lr) * LDK + kt * 32 + q * 8;
      ah[kt] = *(const f16x8*)(Ph + off);
      al[kt] = *(const f16x8*)(Pl + off);
    }
  }
  // direct rows 0..31 (kt0 only), issued early
  const bool need0 = wrow || mt == 0;
  const bool need1 = wrow || mt <= 1;
  float dir0[8], dir1[8];
  if (need0) {
    const float* p = Acur + lr * 128 + q * 8;
    *(float4*)&dir0[0] = *(const float4*)p;
    *(float4*)&dir0[4] = *(const float4*)(p + 4);
  }
  if (need1) {
    const float* p = Acur + (16 + lr) * 128 + q * 8;
    *(float4*)&dir1[0] = *(const float4*)p;
    *(float4*)&dir1[4] = *(const float4*)(p + 4);
  }
  f32x4 acc[8];
#pragma unroll
  for (int nt = 0; nt < 8; ++nt) acc[nt] = (f32x4){0.f, 0.f, 0.f, 0.f};
#pragma unroll
  for (int nt = 2; nt < 8; ++nt) {
    if (wrow || nt >= mt) {
#pragma unroll
      for (int kt = 0; kt < 4; ++kt) {
        if (kt >= ktA0 && kt <= (nt >> 1)) {
          f16x8 ch, cl;
          read_staged(Ast, nt, kt, lr, q, ch, cl);
          acc[nt] = mfma3(ah[kt], al[kt], ch, cl, acc[nt]);
        }
      }
    }
  }
  if (need0) {
    f16x8 ch, cl;
    split8(dir0, ch, cl);
    acc[0] = mfma3(ah[0], al[0], ch, cl, acc[0]);
  }
  if (need1) {
    f16x8 ch, cl;
    split8(dir1, ch, cl);
    acc[1] = mfma3(ah[0], al[0], ch, cl, acc[1]);
  }
  __syncthreads();  // all Ast reads + state reads complete
  if (Anext) issue_A(Anext, Ast, soff, tid);  // async overwrite, drained at next barrier
#pragma unroll
  for (int nt = 0; nt < 8; ++nt) {
    if (!(wrow || nt >= mt)) continue;
    float v[4] = {acc[nt][0], acc[nt][1], acc[nt][2], acc[nt][3]};
    if (wrow) {
      const int b0 = (mt - 8) * 16 + q * 4;
      const float4 x4 = *(const float4*)(x32 + b0);
      const float bn = Bvl[nt * 16 + lr];
      v[0] += bn * x4.x; v[1] += bn * x4.y; v[2] += bn * x4.z; v[3] += bn * x4.w;
    }
#pragma unroll
    for (int r = 0; r < 4; ++r) {
      const int o = (wv * 16 + q * 4 + r) * LDK + nt * 16 + lr;
      const f16 hh = (f16)v[r];
      Ph[o] = hh;
      Pl[o] = (f16)(v[r] - (float)hh);
    }
  }
  __syncthreads();
}

// copy P' (= result^T in LDS) out as PLAIN M (f16 hi/lo) + w (f32 [n][32]).
// Triangular: storage vector [i][y0..y0+7] is skipped (left garbage) when
// (y0>>5) > (i>>5); all readers are tile-gated or zero-fill that region.
__device__ __forceinline__ void chain_copyout(const f16* __restrict__ Ph,
                                              const f16* __restrict__ Pl, int h,
                                              f16* __restrict__ oMh,
                                              f16* __restrict__ oMl,
                                              float* __restrict__ oW) {
  const int tid = threadIdx.x;
  for (int t = tid; t < 1024; t += 320) {
    const int i = t >> 3;
    const int slot = (t >> 1) & 3;
    const int half = t & 1;
    const int mtg = slot2mt(h, slot);
    const int y0 = mtg * 16 + half * 8;
    if ((y0 >> 5) > (i >> 5)) continue;  // zero tile: skip store
    f16x8 hv, lv;
#pragma unroll
    for (int e = 0; e < 8; ++e) {
      hv[e] = Ph[(slot * 16 + half * 8 + e) * LDK + i];
      lv[e] = Pl[(slot * 16 + half * 8 + e) * LDK + i];
    }
    *(f16x8*)(oMh + i * 128 + y0) = hv;
    *(f16x8*)(oMl + i * 128 + y0) = lv;
  }
  for (int t = tid; t < 512; t += 320) {
    const int n = t >> 2, b4 = (t & 3) * 4;
    float4 o;
    float* po = (float*)&o;
#pragma unroll
    for (int e = 0; e < 4; ++e)
      po[e] = (float)Ph[(64 + b4 + e) * LDK + n] + (float)Pl[(64 + b4 + e) * LDK + n];
    *(float4*)(oW + n * 32 + h * 16 + b4) = o;
  }
}

// ---------------------------------------------------------------------------
// state_step_h (b16 path): 16-row state <- state * B^T (+w add). Works with
// >=256 threads; waves 0..3 compute, extra waves barrier only.
__device__ __forceinline__ void state_step_h_b16(const f16* __restrict__ Bh16,
                                                 const f16* __restrict__ Bl16,
                                                 const float* __restrict__ aux0,
                                                 f16* __restrict__ Sh,
                                                 f16* __restrict__ Sl, int h) {
  const int tid = threadIdx.x;
  const int wv4 = tid >> 6;
  const bool act = (wv4 < 4);
  const int wv = wv4 & 3;
  const int lane = tid & 63, lr = lane & 15, q = lane >> 4;
  const int nts[2] = {wv, 7 - wv};
  const int ktAmax = (7 - wv) >> 1;
  f16x8 ah[4], al[4];
  f16x8 bh[2][4], bl[2][4];
  f32x4 acc[2];
  if (act) {
#pragma unroll
    for (int kt = 0; kt < 4; ++kt)
      if (kt <= ktAmax) {
        const int off = lr * LDK + kt * 32 + q * 8;
        ah[kt] = *(const f16x8*)(Sh + off);
        al[kt] = *(const f16x8*)(Sl + off);
      }
#pragma unroll
    for (int ni = 0; ni < 2; ++ni) {
      const int nt = nts[ni];
#pragma unroll
      for (int kt = 0; kt < 4; ++kt)
        if (kt <= (nt >> 1)) {
          const int o = (nt * 16 + lr) * 128 + kt * 32 + q * 8;
          bh[ni][kt] = *(const f16x8*)(Bh16 + o);
          bl[ni][kt] = *(const f16x8*)(Bl16 + o);
        }
    }
#pragma unroll
    for (int ni = 0; ni < 2; ++ni) acc[ni] = (f32x4){0.f, 0.f, 0.f, 0.f};
#pragma unroll
    for (int ni = 0; ni < 2; ++ni) {
      const int nt = nts[ni];
#pragma unroll
      for (int kt = 0; kt < 4; ++kt)
        if (kt <= (nt >> 1))
          acc[ni] = mfma3(ah[kt], al[kt], bh[ni][kt], bl[ni][kt], acc[ni]);
    }
  }
  __syncthreads();
  if (act) {
#pragma unroll
    for (int ni = 0; ni < 2; ++ni) {
      const int nt = nts[ni];
      float v[4] = {acc[ni][0], acc[ni][1], acc[ni][2], acc[ni][3]};
      const int bq = q * 4;
      const float4 w4 = *(const float4*)(aux0 + (nt * 16 + lr) * 32 + h * 16 + bq);
      v[0] += w4.x; v[1] += w4.y; v[2] += w4.z; v[3] += w4.w;
#pragma unroll
      for (int r = 0; r < 4; ++r) {
        const int o = (bq + r) * LDK + nt * 16 + lr;
        const f16 hh = (f16)v[r];
        Sh[o] = hh;
        Sl[o] = (f16)(v[r] - (float)hh);
      }
    }
  }
  __syncthreads();
}

// state_step_h_staged: B from staged LDS (nt>=2) + direct regs (nt<2 on wv<2).
// Issues next step's A staging between barriers. EXTRA==1 semantics + out.
__device__ __forceinline__ void state_step_h_staged(
    const float* __restrict__ Acur, const float* __restrict__ Anext,
    const float* __restrict__ x32, const float* __restrict__ Bvl,
    f16* __restrict__ Sh, f16* __restrict__ Sl, float* __restrict__ outp,
    int h, float* __restrict__ Ast, const int (&soff)[8]) {
  const int tid = threadIdx.x;
  const int wv4 = tid >> 6;
  const bool act = (wv4 < 4);
  const int wv = wv4 & 3;
  const int lane = tid & 63, lr = lane & 15, q = lane >> 4;
  const int ntL = wv, ntH = 7 - wv;
  f32x4 accL = (f32x4){0.f, 0.f, 0.f, 0.f}, accH = accL;
  if (act) {
    const int ktAmax = ntH >> 1;
    f16x8 ah[4], al[4];
#pragma unroll
    for (int kt = 0; kt < 4; ++kt)
      if (kt <= ktAmax) {
        const int off = lr * LDK + kt * 32 + q * 8;
        ah[kt] = *(const f16x8*)(Sh + off);
        al[kt] = *(const f16x8*)(Sl + off);
      }
    float dir[8];
    if (wv < 2) {  // ntL in {0,1}: direct kt0 rows
      const float* p = Acur + (ntL * 16 + lr) * 128 + q * 8;
      *(float4*)&dir[0] = *(const float4*)p;
      *(float4*)&dir[4] = *(const float4*)(p + 4);
    }
    // staged high nt (4..7)
#pragma unroll
    for (int kt = 0; kt < 4; ++kt) {
      if (kt <= (ntH >> 1)) {
        f16x8 ch, cl;
        read_staged(Ast, ntH, kt, lr, q, ch, cl);
        accH = mfma3(ah[kt], al[kt], ch, cl, accH);
      }
    }
    if (wv >= 2) {  // ntL in {2,3}: staged
#pragma unroll
      for (int kt = 0; kt < 4; ++kt) {
        if (kt <= (ntL >> 1)) {
          f16x8 ch, cl;
          read_staged(Ast, ntL, kt, lr, q, ch, cl);
          accL = mfma3(ah[kt], al[kt], ch, cl, accL);
        }
      }
    } else {
      f16x8 ch, cl;
      split8(dir, ch, cl);
      accL = mfma3(ah[0], al[0], ch, cl, accL);
    }
  }
  __syncthreads();
  if (Anext) issue_A(Anext, Ast, soff, tid);
  if (act) {
#pragma unroll
    for (int ni = 0; ni < 2; ++ni) {
      const int nt = (ni == 0) ? ntL : ntH;
      const f32x4 a = (ni == 0) ? accL : accH;
      float v[4] = {a[0], a[1], a[2], a[3]};
      const int bq = q * 4;
      const float4 x4 = *(const float4*)(x32 + h * 16 + bq);
      const float bn = Bvl[nt * 16 + lr];
      v[0] += bn * x4.x; v[1] += bn * x4.y; v[2] += bn * x4.z; v[3] += bn * x4.w;
      if (outp) {
#pragma unroll
        for (int r = 0; r < 4; ++r)
          outp[(h * 16 + bq + r) * 128 + nt * 16 + lr] = v[r];
      }
#pragma unroll
      for (int r = 0; r < 4; ++r) {
        const int o = (bq + r) * LDK + nt * 16 + lr;
        const f16 hh = (f16)v[r];
        Sh[o] = hh;
        Sl[o] = (f16)(v[r] - (float)hh);
      }
    }
  }
  __syncthreads();
}

// ---------------------------------------------------------------------------
// K1: chunk units. grid 512 (c = bid>>1, h = bid&1), 320 threads. writes set A.
__global__ __launch_bounds__(320) void k1_chunks(const float* __restrict__ A,
                                                 const float* __restrict__ x,
                                                 const float* __restrict__ Bv,
                                                 f16* __restrict__ Mh,
                                                 f16* __restrict__ Ml,
                                                 float* __restrict__ Wf) {
  __shared__ f16 Ph[80 * LDK], Pl[80 * LDK];
  __shared__ float Ast[9216];
  const int tid = threadIdx.x;
  const int c = blockIdx.x >> 1, h = blockIdx.x & 1;
  const int l0 = 4 * c;
  int soff[8];
  compute_soff(tid, soff);
  issue_A(A + (size_t)(l0 + 1) * 16384, Ast, soff, tid);  // stage step 1 early
  const float* A0 = A + (size_t)l0 * 16384;
  for (int t = tid; t < 2048; t += 320) {
    const int k = t >> 4, u = t & 15;
    const int slot = u >> 2, fo = (u & 3) * 4;
    const int mtg = slot2mt(h, slot);
    const int y = mtg * 16 + fo;
    float vv[4];
    if ((y >> 5) <= (k >> 5)) {  // triangular: upper tiles are zero
      const float4 v = *(const float4*)(A0 + k * 128 + y);
      vv[0] = v.x; vv[1] = v.y; vv[2] = v.z; vv[3] = v.w;
    } else {
      vv[0] = vv[1] = vv[2] = vv[3] = 0.f;
    }
#pragma unroll
    for (int e = 0; e < 4; ++e) {
      const f16 hh = (f16)vv[e];
      Ph[(slot * 16 + fo + e) * LDK + k] = hh;
      Pl[(slot * 16 + fo + e) * LDK + k] = (f16)(vv[e] - (float)hh);
    }
  }
  for (int t = tid; t < 512; t += 320) {
    const int b = t >> 5, n4 = (t & 31) * 4;
    const float xb = x[l0 * 32 + h * 16 + b];
#pragma unroll
    for (int e = 0; e < 4; ++e) {
      const float u = xb * Bv[l0 * 128 + n4 + e];
      const f16 hh = (f16)u;
      Ph[(64 + b) * LDK + n4 + e] = hh;
      Pl[(64 + b) * LDK + n4 + e] = (f16)(u - (float)hh);
    }
  }
  __syncthreads();  // drains vmcnt: staged A for step 1 ready
  const int wv = tid >> 6;
  const int mt = (wv == 4) ? (8 + h) : slot2mt(h, wv);
  chain_step_k1(A + (size_t)(l0 + 1) * 16384, A + (size_t)(l0 + 2) * 16384,
                x + (l0 + 1) * 32, Bv + (l0 + 1) * 128, Ph, Pl, Ast, soff, wv, mt);
  chain_step_k1(A + (size_t)(l0 + 2) * 16384, A + (size_t)(l0 + 3) * 16384,
                x + (l0 + 2) * 32, Bv + (l0 + 2) * 128, Ph, Pl, Ast, soff, wv, mt);
  chain_step_k1(A + (size_t)(l0 + 3) * 16384, nullptr,
                x + (l0 + 3) * 32, Bv + (l0 + 3) * 128, Ph, Pl, Ast, soff, wv, mt);
  chain_copyout(Ph, Pl, h, Mh + (size_t)c * 16384, Ml + (size_t)c * 16384,
                Wf + (size_t)c * 4096);
}

// ---------------------------------------------------------------------------
// mscan_w: per-wave barrier-free within-group matrix prefix scan.
// grid 160 (bid -> g = bid/10, u = bid%10: h = u/5, slot = u%5), 64 threads.
// Each wave owns one m-tile (4 matrix tiles + 1 w-tile per (g,h)) of the
// running prefix, kept in private LDS; 15 serial steps, B from set A global,
// per-nt double-buffer + cross-step prefetch. Writes set B nodes 16g+j.
__global__ __launch_bounds__(64) void mscan_w(const f16* __restrict__ MhA,
                                              const f16* __restrict__ MlA,
                                              const float* __restrict__ WA,
                                              f16* __restrict__ MhB,
                                              f16* __restrict__ MlB,
                                              float* __restrict__ WB) {
  __shared__ f16 Ph[16 * LDK], Pl[16 * LDK];
  const int bid = blockIdx.x;
  const int g = bid / 10, u = bid - 10 * g;
  const int h = u / 5, slot = u - 5 * (u / 5);
  const int mt = (slot == 4) ? (8 + h) : slot2mt(h, slot);
  const bool wrow = (mt >= 8);
  const int lane = threadIdx.x & 63;
  const int lr = lane & 15, q = lane >> 4;
  const size_t n0 = (size_t)(16 * g);
  const int ktA0 = wrow ? 0 : (mt >> 1);
  const int ntF = wrow ? 0 : mt;

  // ---- init P-tile from node n0 (set A); no barrier (same-wave LDS) ----
  if (!wrow) {
    const f16* pMh = MhA + n0 * 16384;
    const f16* pMl = MlA + n0 * 16384;
#pragma unroll
    for (int it = 0; it < 4; ++it) {
      const int t = lane + it * 64;
      const int k = t >> 1, half = t & 1;
      const int y0 = mt * 16 + half * 8;
      f16x8 hv, lv;
      if ((y0 >> 5) <= (k >> 5)) {
        hv = *(const f16x8*)(pMh + k * 128 + y0);
        lv = *(const f16x8*)(pMl + k * 128 + y0);
      } else {
#pragma unroll
        for (int e = 0; e < 8; ++e) { hv[e] = (f16)0.f; lv[e] = (f16)0.f; }
      }
#pragma unroll
      for (int e = 0; e < 8; ++e) {
        Ph[(half * 8 + e) * LDK + k] = hv[e];
        Pl[(half * 8 + e) * LDK + k] = lv[e];
      }
    }
  } else {
    const float* pW = WA + n0 * 4096;
#pragma unroll
    for (int it = 0; it < 8; ++it) {
      const int t = lane + it * 64;
      const int n = t >> 2, b4 = (t & 3) * 4;
      const float4 w4 = *(const float4*)(pW + n * 32 + h * 16 + b4);
      const float vv[4] = {w4.x, w4.y, w4.z, w4.w};
#pragma unroll
      for (int r = 0; r < 4; ++r) {
        const f16 hh = (f16)vv[r];
        Ph[(b4 + r) * LDK + n] = hh;
        Pl[(b4 + r) * LDK + n] = (f16)(vv[r] - (float)hh);
      }
    }
  }
  // initial fragments
  f16x8 ah[4], al[4];
#pragma unroll
  for (int kt = 0; kt < 4; ++kt)
    if (kt >= ktA0) {
      const int off = lr * LDK + kt * 32 + q * 8;
      ah[kt] = *(const f16x8*)(Ph + off);
      al[kt] = *(const f16x8*)(Pl + off);
    }

  f16x8 b16h[2][4], b16l[2][4];
  const f16* cBh = MhA + (n0 + 1) * 16384;
  const f16* cBl = MlA + (n0 + 1) * 16384;
  auto loadB = [&](int nt, int s) {
#pragma unroll
    for (int kt = 0; kt < 4; ++kt) {
      if (kt >= ktA0 && kt <= (nt >> 1)) {
        const int o = (nt * 16 + lr) * 128 + kt * 32 + q * 8;
        b16h[s][kt] = *(const f16x8*)(cBh + o);
        b16l[s][kt] = *(const f16x8*)(cBl + o);
      }
    }
  };
  loadB(ntF, ntF & 1);

#pragma unroll 1
  for (int j = 1; j <= 15; ++j) {
    const size_t nd = n0 + j;
    float4 w4s[8];
    if (wrow) {
      const float* Wn = WA + nd * 4096;
      const int b0 = h * 16 + q * 4;
#pragma unroll
      for (int nt = 0; nt < 8; ++nt)
        w4s[nt] = *(const float4*)(Wn + (nt * 16 + lr) * 32 + b0);
    }
    f32x4 acc[8];
#pragma unroll
    for (int nt = 0; nt < 8; ++nt) acc[nt] = (f32x4){0.f, 0.f, 0.f, 0.f};
#pragma unroll
    for (int nt = 0; nt < 8; ++nt) {
      const int cur = nt & 1;
      if (nt < 7 && (nt + 1) > ntF) loadB(nt + 1, cur ^ 1);
      if (nt >= ntF) {
#pragma unroll
        for (int kt = 0; kt < 4; ++kt)
          if (kt >= ktA0 && kt <= (nt >> 1))
            acc[nt] = mfma3(ah[kt], al[kt], b16h[cur][kt], b16l[cur][kt], acc[nt]);
      }
    }
    // cross-step prefetch: next node's first B-tile flies during the epilogue
    if (j < 15) {
      cBh += 16384;
      cBl += 16384;
      loadB(ntF, ntF & 1);
    }
    // writeback new P (hi/lo) to private LDS
#pragma unroll
    for (int nt = 0; nt < 8; ++nt) {
      if (nt < ntF) continue;
      float v[4] = {acc[nt][0], acc[nt][1], acc[nt][2], acc[nt][3]};
      if (wrow) {
        v[0] += w4s[nt].x; v[1] += w4s[nt].y; v[2] += w4s[nt].z; v[3] += w4s[nt].w;
      }
#pragma unroll
      for (int r = 0; r < 4; ++r) {
        const int o = (q * 4 + r) * LDK + nt * 16 + lr;
        const f16 hh = (f16)v[r];
        Ph[o] = hh;
        Pl[o] = (f16)(v[r] - (float)hh);
      }
    }
    // copyout this prefix to set B node nd (coalesced from LDS)
    if (!wrow) {
      f16* oMh = MhB + nd * 16384;
      f16* oMl = MlB + nd * 16384;
#pragma unroll
      for (int it = 0; it < 4; ++it) {
        const int t = lane + it * 64;
        const int k = t >> 1, half = t & 1;
        const int y0 = mt * 16 + half * 8;
        if ((y0 >> 5) > (k >> 5)) continue;  // triangular: skip zero tile
        f16x8 hv, lv;
#pragma unroll
        for (int e = 0; e < 8; ++e) {
          hv[e] = Ph[(half * 8 + e) * LDK + k];
          lv[e] = Pl[(half * 8 + e) * LDK + k];
        }
        *(f16x8*)(oMh + k * 128 + y0) = hv;
        *(f16x8*)(oMl + k * 128 + y0) = lv;
      }
    } else {
      float* oW = WB + nd * 4096;
#pragma unroll
      for (int it = 0; it < 8; ++it) {
        const int t = lane + it * 64;
        const int n = t >> 2, b4 = (t & 3) * 4;
        float4 o;
        float* po = (float*)&o;
#pragma unroll
        for (int e = 0; e < 4; ++e)
          po[e] = (float)Ph[(b4 + e) * LDK + n] + (float)Pl[(b4 + e) * LDK + n];
        *(float4*)(oW + n * 32 + h * 16 + b4) = o;
      }
    }
    // fragment reload for next step
    if (j < 15) {
#pragma unroll
      for (int kt = 0; kt < 4; ++kt)
        if (kt >= ktA0) {
          const int off = lr * LDK + kt * 32 + q * 8;
          ah[kt] = *(const f16x8*)(Ph + off);
          al[kt] = *(const f16x8*)(Pl + off);
        }
    }
  }
}

// ---------------------------------------------------------------------------
// gscan: serial Horner state scan over the 16 group totals (set B nodes
// 16t+15). grid 32 (g = bid>>1, h = bid&1), 256 threads.
// Writes entry states Ef[g] as f32 [n][32] (g=0 -> zeros).
__global__ __launch_bounds__(256) void gscan(const f16* __restrict__ MhB,
                                             const f16* __restrict__ MlB,
                                             const float* __restrict__ WB,
                                             float* __restrict__ Ef) {
  __shared__ f16 Sh[16 * LDK], Sl[16 * LDK];
  const int g = blockIdx.x >> 1, h = blockIdx.x & 1;
  const int tid = threadIdx.x;
  for (int t = tid; t < 16 * LDK; t += 256) { Sh[t] = (f16)0.f; Sl[t] = (f16)0.f; }
  __syncthreads();
#pragma unroll 1
  for (int t = 0; t < g; ++t) {
    const size_t nd = (size_t)(16 * t + 15);
    state_step_h_b16(MhB + nd * 16384, MlB + nd * 16384, WB + nd * 4096,
                     Sh, Sl, h);
  }
  for (int t = tid; t < 2048; t += 256) {
    const int row = t & 15, n = t >> 4;
    Ef[(size_t)g * 4096 + n * 32 + h * 16 + row] =
        (float)Sh[row * LDK + n] + (float)Sl[row * LDK + n];
  }
}

// ---------------------------------------------------------------------------
// K3 h-split: grid 512 (c = bid>>1, h = bid&1), 320 thr, 16 batch rows each.
// entry = Ef[g] (f32); if j>0 apply chunk prefix c-1 ((j-1)==0 -> set A,
// else set B); replay 4 timesteps.
__global__ __launch_bounds__(320) void k3h(const float* __restrict__ A,
                                           const float* __restrict__ x,
                                           const float* __restrict__ Bv,
                                           const f16* __restrict__ MhA,
                                           const f16* __restrict__ MlA,
                                           const float* __restrict__ WA,
                                           const f16* __restrict__ MhB,
                                           const f16* __restrict__ MlB,
                                           const float* __restrict__ WB,
                                           const float* __restrict__ Ef,
                                           float* __restrict__ out) {
  __shared__ f16 Sh[16 * LDK], Sl[16 * LDK];
  __shared__ float Ast[9216];
  const int tid = threadIdx.x;
  const int c = blockIdx.x >> 1, h = blockIdx.x & 1;
  const int g = c >> 4, j = c & 15;
  int soff[8];
  compute_soff(tid, soff);
  issue_A(A + (size_t)(4 * c) * 16384, Ast, soff, tid);  // stage t4=0 early
  const float* Ew = Ef + (size_t)g * 4096;
  for (int tt = tid; tt < 2048; tt += 320) {
    const int row = tt & 15, n = tt >> 4;
    const float v = Ew[n * 32 + h * 16 + row];
    const f16 hh = (f16)v;
    Sh[row * LDK + n] = hh;
    Sl[row * LDK + n] = (f16)(v - (float)hh);
  }
  __syncthreads();  // drains vmcnt: staged A for t4=0 ready
  if (j > 0) {
    const int nd = c - 1, jp = j - 1;  // jp = within-group index of prefix node
    const bool inA = (jp == 0);        // j'==0: prefix = chunk itself (set A)
    const f16* mh = (inA ? MhA : MhB) + (size_t)nd * 16384;
    const f16* ml = (inA ? MlA : MlB) + (size_t)nd * 16384;
    const float* w = (inA ? WA : WB) + (size_t)nd * 4096;
    state_step_h_b16(mh, ml, w, Sh, Sl, h);
  }
#pragma unroll 1
  for (int t4 = 0; t4 < 4; ++t4) {
    const int l = 4 * c + t4;
    const float* Anext = (t4 < 3) ? A + (size_t)(l + 1) * 16384 : nullptr;
    state_step_h_staged(A + (size_t)l * 16384, Anext, x + l * 32, Bv + l * 128,
                        Sh, Sl, out + (size_t)l * 4096, h, Ast, soff);
  }
}

// ---------------------------------------------------------------------------
extern "C" void kernel_launch(void* const* d_in, const int* in_sizes, int n_in,
                              void* d_out, int out_size, void* d_ws, size_t ws_size,
                              hipStream_t stream) {
  const float* x  = (const float*)d_in[0];  // (1024, 32)
  const float* A  = (const float*)d_in[1];  // (1024, 128, 128) lower-triangular
  const float* Bv = (const float*)d_in[2];  // (1024, 128)
  float* out = (float*)d_out;               // (1024, 32, 128)

  // set A: chunk units (k1 output)
  f16* MhA = (f16*)d_ws;                    // 256*16384 f16
  f16* MlA = MhA + 256 * 16384;
  float* WA = (float*)(MlA + 256 * 16384);  // 256*4096 f32
  // set B: within-group prefixes j>=1 (mscan output)
  f16* MhB = (f16*)(WA + 256 * 4096);
  f16* MlB = MhB + 256 * 16384;
  float* WB = (float*)(MlB + 256 * 16384);
  // entry states (f32)
  float* Ef = WB + 256 * 4096;              // 16*4096 f32; total ~42.2 MB

  k1_chunks<<<512, 320, 0, stream>>>(A, x, Bv, MhA, MlA, WA);
  mscan_w<<<160, 64, 0, stream>>>(MhA, MlA, WA, MhB, MlB, WB);
  gscan<<<32, 256, 0, stream>>>(MhB, MlB, WB, Ef);
  k3h<<<512, 320, 0, stream>>>(A, x, Bv, MhA, MlA, WA, MhB, MlB, WB, Ef, out);
}

// Round 6
// 292.159 us; speedup vs baseline: 1.7663x; 1.7663x over previous
//
#include <hip/hip_runtime.h>

// HiPPO-LegS scan — round 12: revert mscan to round-10 block structure,
// kill its exposed B-load latency with packed-triangular LDS staging.
//  * Round-11 mscan_w (160 1-wave blocks) was a disaster: <=1 wave/CU, zero
//    TLP, 10x FETCH amplification, 324 µs. Reverted.
//  * mscan (32 blk x 320 thr, round-10 verified): node j+1's triangular M
//    (f16 hi+lo) staged via global_load_lds into an LDS double buffer between
//    step j's barriers (k1's proven pattern). Packed bands of 32 rows, chunk
//    counts padded to {4,8,16,16}/row, XOR-swizzled chunk-in-row (bijective);
//    linear LDS dest + per-lane permuted global source + mirrored read.
//    Step compute reads B via ds_read_b128 (<=2-way conflict) instead of
//    ~500cy global round-trips.
//  * gscan: same staging for its serial chain of group-total M reads.
//  * k1 / k3h unchanged.
// Pipeline: k1(512) -> mscan(32) -> gscan(32) -> k3h(512). 4 launches.

#define LDK 136   // f16 k-stride of LDS state rows
#define PKF 11264 // f16 per packed triangular matrix (22528 B)

using f16 = _Float16;
typedef __attribute__((ext_vector_type(8))) f16 f16x8;
typedef __attribute__((ext_vector_type(4))) float f32x4;

__device__ __forceinline__ f32x4 mfma3(f16x8 ah, f16x8 al, f16x8 bh, f16x8 bl,
                                       f32x4 c) {
  c = __builtin_amdgcn_mfma_f32_16x16x32_f16(ah, bh, c, 0, 0, 0);
  c = __builtin_amdgcn_mfma_f32_16x16x32_f16(ah, bl, c, 0, 0, 0);
  c = __builtin_amdgcn_mfma_f32_16x16x32_f16(al, bh, c, 0, 0, 0);
  return c;
}

__device__ __forceinline__ void split8(const float* v, f16x8& h, f16x8& l) {
#pragma unroll
  for (int j = 0; j < 8; ++j) {
    const float x = v[j];
    const f16 hh = (f16)x;
    h[j] = hh;
    l[j] = (f16)(x - (float)hh);
  }
}

// global m-tile owned by (h, slot): h=0 -> {0,7,1,6}, h=1 -> {2,5,3,4}
__device__ __forceinline__ int slot2mt(int h, int slot) {
  if (h == 0) return (slot & 1) ? 7 - (slot >> 1) : (slot >> 1);
  return (slot & 1) ? 5 - (slot >> 1) : 2 + (slot >> 1);
}

__device__ __forceinline__ void gload_lds16(const float* g, float* l) {
  __builtin_amdgcn_global_load_lds(
      (const __attribute__((address_space(1))) unsigned int*)g,
      (__attribute__((address_space(3))) unsigned int*)l, 16, 0, 0);
}

// ---------------------------------------------------------------------------
// Packed triangular matrix staging (f16). Bands of 32 rows; chunks(16B)/row
// padded to {4,8,16,16}; chunk-in-row XOR-swizzled by (ri & (cc-1)) —
// bijective per band. 1408 chunks = PKF f16 = 22528 B per matrix.
// f16 band bases {0,1024,3072,7168}; chunk bases {0,128,384,896}.

__device__ __forceinline__ int pk_src_off(int m) {  // global f16 offset of chunk m
  int b, local, ccm1, sh;
  if (m < 128)      { b = 0; local = m;       ccm1 = 3;  sh = 2; }
  else if (m < 384) { b = 1; local = m - 128; ccm1 = 7;  sh = 3; }
  else if (m < 896) { b = 2; local = m - 384; ccm1 = 15; sh = 4; }
  else              { b = 3; local = m - 896; ccm1 = 15; sh = 4; }
  const int ri = local >> sh, cp = local & ccm1;
  const int c = cp ^ (ri & ccm1);  // source chunk held in LDS slot cp
  return (b * 32 + ri) * 128 + c * 8;
}

// read source chunk j0 (= kt*4+q) of row nt*16+lr from a packed matrix
__device__ __forceinline__ void read_pk(const f16* __restrict__ Bs, int nt,
                                        int lr, int j0, f16x8& v) {
  const int b = nt >> 1;
  const int ri = ((nt & 1) << 4) + lr;
  const int ccm1 = (b == 0) ? 3 : (b == 1) ? 7 : 15;
  const int fb = (b == 0) ? 0 : (b == 1) ? 1024 : (b == 2) ? 3072 : 7168;
  const int c = j0 ^ (ri & ccm1);
  v = *(const f16x8*)(Bs + fb + ri * ((ccm1 + 1) * 8) + c * 8);
}

template <int NT, int IT>
__device__ __forceinline__ void pk_precompute(int tid, int (&src)[IT]) {
#pragma unroll
  for (int it = 0; it < IT; ++it) {
    const int m = tid + it * NT;
    src[it] = (m < 1408) ? pk_src_off(m) : 0;
  }
}

template <int NT, int IT>
__device__ __forceinline__ void pk_stage(const f16* __restrict__ gMh,
                                         const f16* __restrict__ gMl,
                                         f16* __restrict__ dH,
                                         f16* __restrict__ dL,
                                         const int (&src)[IT], int tid) {
#pragma unroll
  for (int it = 0; it < IT; ++it) {
    const int m = tid + it * NT;
    if (it < IT - 1 || m < 1408) {
      gload_lds16((const float*)(gMh + src[it]), (float*)(dH + m * 8));
      gload_lds16((const float*)(gMl + src[it]), (float*)(dL + m * 8));
    }
  }
}

// ---------------------------------------------------------------------------
// Staged-A layout for k1/k3h (f32, LDS, 9216 floats = 36 KB) — unchanged.
__device__ __forceinline__ void compute_soff(int tid, int (&soff)[8]) {
#pragma unroll
  for (int it = 0; it < 8; ++it) {
    const int m = tid + it * 320;
    if (m < 2304) {
      const int kt = (m >= 768) + (m >= 1536) + (m >= 2048);
      const int local = m - ((kt >= 1) * 768 + (kt >= 2) * 768 + (kt >= 3) * 512);
      const int rp = local >> 3, c = local & 7;
      const int r = rp + 32 + (kt >= 2) * 32 + (kt >= 3) * 32;
      soff[it] = r * 128 + kt * 32 + ((c ^ (rp & 7)) << 2);
    } else {
      soff[it] = 0;
    }
  }
}

__device__ __forceinline__ void issue_A(const float* __restrict__ Al,
                                        float* __restrict__ Ast,
                                        const int (&soff)[8], int tid) {
#pragma unroll
  for (int it = 0; it < 8; ++it) {
    if (it < 7 || tid < 64)
      gload_lds16(Al + soff[it], Ast + (tid + it * 320) * 4);
  }
}

__device__ __forceinline__ void read_staged(const float* __restrict__ Ast,
                                            int nt, int kt, int lr, int q,
                                            f16x8& ch, f16x8& cl) {
  const int rp = nt * 16 + lr - (32 + (kt >= 2) * 32 + (kt >= 3) * 32);
  const float* pb =
      Ast + ((kt >= 1) * 3072 + (kt >= 2) * 3072 + (kt >= 3) * 2048) + rp * 32;
  float raw[8];
  *(float4*)&raw[0] = *(const float4*)(pb + (((2 * q + 0) ^ (rp & 7)) << 2));
  *(float4*)&raw[4] = *(const float4*)(pb + (((2 * q + 1) ^ (rp & 7)) << 2));
  split8(raw, ch, cl);
}

// ---------------------------------------------------------------------------
// chain_step_pk: P' <- P' * B^T with B from packed staged LDS; issues next
// node's staging between the two barriers. EXTRA==2 w-add from aux0 (global).
__device__ __forceinline__ void chain_step_pk(
    const f16* __restrict__ Bsh, const f16* __restrict__ Bsl,
    const float* __restrict__ aux0, f16* __restrict__ Ph, f16* __restrict__ Pl,
    int wv, int mt, const f16* __restrict__ nMh, const f16* __restrict__ nMl,
    f16* __restrict__ stH, f16* __restrict__ stL, const int (&src)[5],
    int tid) {
  const int lane = tid & 63;
  const int lr = lane & 15, q = lane >> 4;
  const bool wrow = (mt >= 8);
  const int ktA0 = wrow ? 0 : (mt >> 1);
  f16x8 ah[4], al[4];
#pragma unroll
  for (int kt = 0; kt < 4; ++kt) {
    if (kt >= ktA0) {
      const int off = (wv * 16 + lr) * LDK + kt * 32 + q * 8;
      ah[kt] = *(const f16x8*)(Ph + off);
      al[kt] = *(const f16x8*)(Pl + off);
    }
  }
  f32x4 acc[8];
#pragma unroll
  for (int nt = 0; nt < 8; ++nt) acc[nt] = (f32x4){0.f, 0.f, 0.f, 0.f};
#pragma unroll
  for (int nt = 0; nt < 8; ++nt) {
    if (wrow || nt >= mt) {
#pragma unroll
      for (int kt = 0; kt < 4; ++kt) {
        if (kt >= ktA0 && kt <= (nt >> 1)) {
          f16x8 bh, bl;
          const int j0 = kt * 4 + q;
          read_pk(Bsh, nt, lr, j0, bh);
          read_pk(Bsl, nt, lr, j0, bl);
          acc[nt] = mfma3(ah[kt], al[kt], bh, bl, acc[nt]);
        }
      }
    }
  }
  __syncthreads();  // staged reads + P reads complete
  if (nMh) pk_stage<320, 5>(nMh, nMl, stH, stL, src, tid);  // async; drained at barrier 2
#pragma unroll
  for (int nt = 0; nt < 8; ++nt) {
    if (!(wrow || nt >= mt)) continue;
    float v[4] = {acc[nt][0], acc[nt][1], acc[nt][2], acc[nt][3]};
    if (wrow) {
      const int b0 = (mt - 8) * 16 + q * 4;
      const float4 w4 = *(const float4*)(aux0 + (nt * 16 + lr) * 32 + b0);
      v[0] += w4.x; v[1] += w4.y; v[2] += w4.z; v[3] += w4.w;
    }
#pragma unroll
    for (int r = 0; r < 4; ++r) {
      const int o = (wv * 16 + q * 4 + r) * LDK + nt * 16 + lr;
      const f16 hh = (f16)v[r];
      Ph[o] = hh;
      Pl[o] = (f16)(v[r] - (float)hh);
    }
  }
  __syncthreads();
}

// ---------------------------------------------------------------------------
// chain_step_k1: B operand from staged f32 LDS (nt>=2) + direct regs (nt<2).
__device__ __forceinline__ void chain_step_k1(const float* __restrict__ Acur,
                                              const float* __restrict__ Anext,
                                              const float* __restrict__ x32,
                                              const float* __restrict__ Bvl,
                                              f16* __restrict__ Ph,
                                              f16* __restrict__ Pl,
                                              float* __restrict__ Ast,
                                              const int (&soff)[8],
                                              int wv, int mt) {
  const int tid = threadIdx.x;
  const int lane = tid & 63, lr = lane & 15, q = lane >> 4;
  const bool wrow = (mt >= 8);
  const int ktA0 = wrow ? 0 : (mt >> 1);
  f16x8 ah[4], al[4];
#pragma unroll
  for (int kt = 0; kt < 4; ++kt) {
    if (kt >= ktA0) {
      const int off = (wv * 16 + lr) * LDK + kt * 32 + q * 8;
      ah[kt] = *(const f16x8*)(Ph + off);
      al[kt] = *(const f16x8*)(Pl + off);
    }
  }
  const bool need0 = wrow || mt == 0;
  const bool need1 = wrow || mt <= 1;
  float dir0[8], dir1[8];
  if (need0) {
    const float* p = Acur + lr * 128 + q * 8;
    *(float4*)&dir0[0] = *(const float4*)p;
    *(float4*)&dir0[4] = *(const float4*)(p + 4);
  }
  if (need1) {
    const float* p = Acur + (16 + lr) * 128 + q * 8;
    *(float4*)&dir1[0] = *(const float4*)p;
    *(float4*)&dir1[4] = *(const float4*)(p + 4);
  }
  f32x4 acc[8];
#pragma unroll
  for (int nt = 0; nt < 8; ++nt) acc[nt] = (f32x4){0.f, 0.f, 0.f, 0.f};
#pragma unroll
  for (int nt = 2; nt < 8; ++nt) {
    if (wrow || nt >= mt) {
#pragma unroll
      for (int kt = 0; kt < 4; ++kt) {
        if (kt >= ktA0 && kt <= (nt >> 1)) {
          f16x8 ch, cl;
          read_staged(Ast, nt, kt, lr, q, ch, cl);
          acc[nt] = mfma3(ah[kt], al[kt], ch, cl, acc[nt]);
        }
      }
    }
  }
  if (need0) {
    f16x8 ch, cl;
    split8(dir0, ch, cl);
    acc[0] = mfma3(ah[0], al[0], ch, cl, acc[0]);
  }
  if (need1) {
    f16x8 ch, cl;
    split8(dir1, ch, cl);
    acc[1] = mfma3(ah[0], al[0], ch, cl, acc[1]);
  }
  __syncthreads();
  if (Anext) issue_A(Anext, Ast, soff, tid);
#pragma unroll
  for (int nt = 0; nt < 8; ++nt) {
    if (!(wrow || nt >= mt)) continue;
    float v[4] = {acc[nt][0], acc[nt][1], acc[nt][2], acc[nt][3]};
    if (wrow) {
      const int b0 = (mt - 8) * 16 + q * 4;
      const float4 x4 = *(const float4*)(x32 + b0);
      const float bn = Bvl[nt * 16 + lr];
      v[0] += bn * x4.x; v[1] += bn * x4.y; v[2] += bn * x4.z; v[3] += bn * x4.w;
    }
#pragma unroll
    for (int r = 0; r < 4; ++r) {
      const int o = (wv * 16 + q * 4 + r) * LDK + nt * 16 + lr;
      const f16 hh = (f16)v[r];
      Ph[o] = hh;
      Pl[o] = (f16)(v[r] - (float)hh);
    }
  }
  __syncthreads();
}

// copy P' out as PLAIN M (f16 hi/lo) + w (f32 [n][32]); triangular-gated.
__device__ __forceinline__ void chain_copyout(const f16* __restrict__ Ph,
                                              const f16* __restrict__ Pl, int h,
                                              f16* __restrict__ oMh,
                                              f16* __restrict__ oMl,
                                              float* __restrict__ oW) {
  const int tid = threadIdx.x;
  for (int t = tid; t < 1024; t += 320) {
    const int i = t >> 3;
    const int slot = (t >> 1) & 3;
    const int half = t & 1;
    const int mtg = slot2mt(h, slot);
    const int y0 = mtg * 16 + half * 8;
    if ((y0 >> 5) > (i >> 5)) continue;  // zero tile: skip store
    f16x8 hv, lv;
#pragma unroll
    for (int e = 0; e < 8; ++e) {
      hv[e] = Ph[(slot * 16 + half * 8 + e) * LDK + i];
      lv[e] = Pl[(slot * 16 + half * 8 + e) * LDK + i];
    }
    *(f16x8*)(oMh + i * 128 + y0) = hv;
    *(f16x8*)(oMl + i * 128 + y0) = lv;
  }
  for (int t = tid; t < 512; t += 320) {
    const int n = t >> 2, b4 = (t & 3) * 4;
    float4 o;
    float* po = (float*)&o;
#pragma unroll
    for (int e = 0; e < 4; ++e)
      po[e] = (float)Ph[(64 + b4 + e) * LDK + n] + (float)Pl[(64 + b4 + e) * LDK + n];
    *(float4*)(oW + n * 32 + h * 16 + b4) = o;
  }
}

// P'-init from a node's plain M + W (triangular-gated); trailing barrier.
__device__ __forceinline__ void load_prev_to_P(const f16* pMh, const f16* pMl,
                                               const float* pW, int h,
                                               f16* Ph, f16* Pl) {
  const int tid = threadIdx.x;
  for (int t = tid; t < 1024; t += 320) {
    const int k = t >> 3, u = t & 7;
    const int slot = u >> 1, half = u & 1;
    const int mtg = slot2mt(h, slot);
    const int y0 = mtg * 16 + half * 8;
    f16x8 hv, lv;
    if ((y0 >> 5) <= (k >> 5)) {
      hv = *(const f16x8*)(pMh + k * 128 + y0);
      lv = *(const f16x8*)(pMl + k * 128 + y0);
    } else {
#pragma unroll
      for (int e = 0; e < 8; ++e) { hv[e] = (f16)0.f; lv[e] = (f16)0.f; }
    }
#pragma unroll
    for (int e = 0; e < 8; ++e) {
      Ph[(slot * 16 + half * 8 + e) * LDK + k] = hv[e];
      Pl[(slot * 16 + half * 8 + e) * LDK + k] = lv[e];
    }
  }
  for (int t = tid; t < 2048; t += 320) {
    const int n = t >> 4, b = t & 15;
    const float wv0 = pW[n * 32 + h * 16 + b];
    const f16 hh = (f16)wv0;
    Ph[(64 + b) * LDK + n] = hh;
    Pl[(64 + b) * LDK + n] = (f16)(wv0 - (float)hh);
  }
  __syncthreads();
}

// ---------------------------------------------------------------------------
// state_step_h_b16: 16-row state <- state * B^T (+w add), B from global.
// Used by k3h prefix-apply (512 blocks: TLP hides latency there).
__device__ __forceinline__ void state_step_h_b16(const f16* __restrict__ Bh16,
                                                 const f16* __restrict__ Bl16,
                                                 const float* __restrict__ aux0,
                                                 f16* __restrict__ Sh,
                                                 f16* __restrict__ Sl, int h) {
  const int tid = threadIdx.x;
  const int wv4 = tid >> 6;
  const bool act = (wv4 < 4);
  const int wv = wv4 & 3;
  const int lane = tid & 63, lr = lane & 15, q = lane >> 4;
  const int nts[2] = {wv, 7 - wv};
  const int ktAmax = (7 - wv) >> 1;
  f16x8 ah[4], al[4];
  f16x8 bh[2][4], bl[2][4];
  f32x4 acc[2];
  if (act) {
#pragma unroll
    for (int kt = 0; kt < 4; ++kt)
      if (kt <= ktAmax) {
        const int off = lr * LDK + kt * 32 + q * 8;
        ah[kt] = *(const f16x8*)(Sh + off);
        al[kt] = *(const f16x8*)(Sl + off);
      }
#pragma unroll
    for (int ni = 0; ni < 2; ++ni) {
      const int nt = nts[ni];
#pragma unroll
      for (int kt = 0; kt < 4; ++kt)
        if (kt <= (nt >> 1)) {
          const int o = (nt * 16 + lr) * 128 + kt * 32 + q * 8;
          bh[ni][kt] = *(const f16x8*)(Bh16 + o);
          bl[ni][kt] = *(const f16x8*)(Bl16 + o);
        }
    }
#pragma unroll
    for (int ni = 0; ni < 2; ++ni) acc[ni] = (f32x4){0.f, 0.f, 0.f, 0.f};
#pragma unroll
    for (int ni = 0; ni < 2; ++ni) {
      const int nt = nts[ni];
#pragma unroll
      for (int kt = 0; kt < 4; ++kt)
        if (kt <= (nt >> 1))
          acc[ni] = mfma3(ah[kt], al[kt], bh[ni][kt], bl[ni][kt], acc[ni]);
    }
  }
  __syncthreads();
  if (act) {
#pragma unroll
    for (int ni = 0; ni < 2; ++ni) {
      const int nt = nts[ni];
      float v[4] = {acc[ni][0], acc[ni][1], acc[ni][2], acc[ni][3]};
      const int bq = q * 4;
      const float4 w4 = *(const float4*)(aux0 + (nt * 16 + lr) * 32 + h * 16 + bq);
      v[0] += w4.x; v[1] += w4.y; v[2] += w4.z; v[3] += w4.w;
#pragma unroll
      for (int r = 0; r < 4; ++r) {
        const int o = (bq + r) * LDK + nt * 16 + lr;
        const f16 hh = (f16)v[r];
        Sh[o] = hh;
        Sl[o] = (f16)(v[r] - (float)hh);
      }
    }
  }
  __syncthreads();
}

// state_step_pk: gscan step with B from packed staged LDS; stages next node
// between barriers. 256 threads (4 waves, all active).
__device__ __forceinline__ void state_step_pk(
    const f16* __restrict__ Bsh, const f16* __restrict__ Bsl,
    const float* __restrict__ aux0, f16* __restrict__ Sh,
    f16* __restrict__ Sl, int h, const f16* __restrict__ nMh,
    const f16* __restrict__ nMl, f16* __restrict__ stH,
    f16* __restrict__ stL, const int (&src)[6], int tid) {
  const int wv = (tid >> 6) & 3;
  const int lane = tid & 63, lr = lane & 15, q = lane >> 4;
  const int nts[2] = {wv, 7 - wv};
  const int ktAmax = (7 - wv) >> 1;
  f16x8 ah[4], al[4];
#pragma unroll
  for (int kt = 0; kt < 4; ++kt)
    if (kt <= ktAmax) {
      const int off = lr * LDK + kt * 32 + q * 8;
      ah[kt] = *(const f16x8*)(Sh + off);
      al[kt] = *(const f16x8*)(Sl + off);
    }
  f32x4 acc[2];
#pragma unroll
  for (int ni = 0; ni < 2; ++ni) acc[ni] = (f32x4){0.f, 0.f, 0.f, 0.f};
#pragma unroll
  for (int ni = 0; ni < 2; ++ni) {
    const int nt = nts[ni];
#pragma unroll
    for (int kt = 0; kt < 4; ++kt)
      if (kt <= (nt >> 1)) {
        f16x8 bh, bl;
        const int j0 = kt * 4 + q;
        read_pk(Bsh, nt, lr, j0, bh);
        read_pk(Bsl, nt, lr, j0, bl);
        acc[ni] = mfma3(ah[kt], al[kt], bh, bl, acc[ni]);
      }
  }
  __syncthreads();
  if (nMh) pk_stage<256, 6>(nMh, nMl, stH, stL, src, tid);
#pragma unroll
  for (int ni = 0; ni < 2; ++ni) {
    const int nt = nts[ni];
    float v[4] = {acc[ni][0], acc[ni][1], acc[ni][2], acc[ni][3]};
    const int bq = q * 4;
    const float4 w4 = *(const float4*)(aux0 + (nt * 16 + lr) * 32 + h * 16 + bq);
    v[0] += w4.x; v[1] += w4.y; v[2] += w4.z; v[3] += w4.w;
#pragma unroll
    for (int r = 0; r < 4; ++r) {
      const int o = (bq + r) * LDK + nt * 16 + lr;
      const f16 hh = (f16)v[r];
      Sh[o] = hh;
      Sl[o] = (f16)(v[r] - (float)hh);
    }
  }
  __syncthreads();
}

// state_step_h_staged: k3h replay step (f32 staged A) — unchanged.
__device__ __forceinline__ void state_step_h_staged(
    const float* __restrict__ Acur, const float* __restrict__ Anext,
    const float* __restrict__ x32, const float* __restrict__ Bvl,
    f16* __restrict__ Sh, f16* __restrict__ Sl, float* __restrict__ outp,
    int h, float* __restrict__ Ast, const int (&soff)[8]) {
  const int tid = threadIdx.x;
  const int wv4 = tid >> 6;
  const bool act = (wv4 < 4);
  const int wv = wv4 & 3;
  const int lane = tid & 63, lr = lane & 15, q = lane >> 4;
  const int ntL = wv, ntH = 7 - wv;
  f32x4 accL = (f32x4){0.f, 0.f, 0.f, 0.f}, accH = accL;
  if (act) {
    const int ktAmax = ntH >> 1;
    f16x8 ah[4], al[4];
#pragma unroll
    for (int kt = 0; kt < 4; ++kt)
      if (kt <= ktAmax) {
        const int off = lr * LDK + kt * 32 + q * 8;
        ah[kt] = *(const f16x8*)(Sh + off);
        al[kt] = *(const f16x8*)(Sl + off);
      }
    float dir[8];
    if (wv < 2) {
      const float* p = Acur + (ntL * 16 + lr) * 128 + q * 8;
      *(float4*)&dir[0] = *(const float4*)p;
      *(float4*)&dir[4] = *(const float4*)(p + 4);
    }
#pragma unroll
    for (int kt = 0; kt < 4; ++kt) {
      if (kt <= (ntH >> 1)) {
        f16x8 ch, cl;
        read_staged(Ast, ntH, kt, lr, q, ch, cl);
        accH = mfma3(ah[kt], al[kt], ch, cl, accH);
      }
    }
    if (wv >= 2) {
#pragma unroll
      for (int kt = 0; kt < 4; ++kt) {
        if (kt <= (ntL >> 1)) {
          f16x8 ch, cl;
          read_staged(Ast, ntL, kt, lr, q, ch, cl);
          accL = mfma3(ah[kt], al[kt], ch, cl, accL);
        }
      }
    } else {
      f16x8 ch, cl;
      split8(dir, ch, cl);
      accL = mfma3(ah[0], al[0], ch, cl, accL);
    }
  }
  __syncthreads();
  if (Anext) issue_A(Anext, Ast, soff, tid);
  if (act) {
#pragma unroll
    for (int ni = 0; ni < 2; ++ni) {
      const int nt = (ni == 0) ? ntL : ntH;
      const f32x4 a = (ni == 0) ? accL : accH;
      float v[4] = {a[0], a[1], a[2], a[3]};
      const int bq = q * 4;
      const float4 x4 = *(const float4*)(x32 + h * 16 + bq);
      const float bn = Bvl[nt * 16 + lr];
      v[0] += bn * x4.x; v[1] += bn * x4.y; v[2] += bn * x4.z; v[3] += bn * x4.w;
      if (outp) {
#pragma unroll
        for (int r = 0; r < 4; ++r)
          outp[(h * 16 + bq + r) * 128 + nt * 16 + lr] = v[r];
      }
#pragma unroll
      for (int r = 0; r < 4; ++r) {
        const int o = (bq + r) * LDK + nt * 16 + lr;
        const f16 hh = (f16)v[r];
        Sh[o] = hh;
        Sl[o] = (f16)(v[r] - (float)hh);
      }
    }
  }
  __syncthreads();
}

// ---------------------------------------------------------------------------
// K1: chunk units. grid 512 (c = bid>>1, h = bid&1), 320 threads. writes set A.
__global__ __launch_bounds__(320) void k1_chunks(const float* __restrict__ A,
                                                 const float* __restrict__ x,
                                                 const float* __restrict__ Bv,
                                                 f16* __restrict__ Mh,
                                                 f16* __restrict__ Ml,
                                                 float* __restrict__ Wf) {
  __shared__ f16 Ph[80 * LDK], Pl[80 * LDK];
  __shared__ float Ast[9216];
  const int tid = threadIdx.x;
  const int c = blockIdx.x >> 1, h = blockIdx.x & 1;
  const int l0 = 4 * c;
  int soff[8];
  compute_soff(tid, soff);
  issue_A(A + (size_t)(l0 + 1) * 16384, Ast, soff, tid);
  const float* A0 = A + (size_t)l0 * 16384;
  for (int t = tid; t < 2048; t += 320) {
    const int k = t >> 4, u = t & 15;
    const int slot = u >> 2, fo = (u & 3) * 4;
    const int mtg = slot2mt(h, slot);
    const int y = mtg * 16 + fo;
    float vv[4];
    if ((y >> 5) <= (k >> 5)) {
      const float4 v = *(const float4*)(A0 + k * 128 + y);
      vv[0] = v.x; vv[1] = v.y; vv[2] = v.z; vv[3] = v.w;
    } else {
      vv[0] = vv[1] = vv[2] = vv[3] = 0.f;
    }
#pragma unroll
    for (int e = 0; e < 4; ++e) {
      const f16 hh = (f16)vv[e];
      Ph[(slot * 16 + fo + e) * LDK + k] = hh;
      Pl[(slot * 16 + fo + e) * LDK + k] = (f16)(vv[e] - (float)hh);
    }
  }
  for (int t = tid; t < 512; t += 320) {
    const int b = t >> 5, n4 = (t & 31) * 4;
    const float xb = x[l0 * 32 + h * 16 + b];
#pragma unroll
    for (int e = 0; e < 4; ++e) {
      const float u = xb * Bv[l0 * 128 + n4 + e];
      const f16 hh = (f16)u;
      Ph[(64 + b) * LDK + n4 + e] = hh;
      Pl[(64 + b) * LDK + n4 + e] = (f16)(u - (float)hh);
    }
  }
  __syncthreads();
  const int wv = tid >> 6;
  const int mt = (wv == 4) ? (8 + h) : slot2mt(h, wv);
  chain_step_k1(A + (size_t)(l0 + 1) * 16384, A + (size_t)(l0 + 2) * 16384,
                x + (l0 + 1) * 32, Bv + (l0 + 1) * 128, Ph, Pl, Ast, soff, wv, mt);
  chain_step_k1(A + (size_t)(l0 + 2) * 16384, A + (size_t)(l0 + 3) * 16384,
                x + (l0 + 2) * 32, Bv + (l0 + 2) * 128, Ph, Pl, Ast, soff, wv, mt);
  chain_step_k1(A + (size_t)(l0 + 3) * 16384, nullptr,
                x + (l0 + 3) * 32, Bv + (l0 + 3) * 128, Ph, Pl, Ast, soff, wv, mt);
  chain_copyout(Ph, Pl, h, Mh + (size_t)c * 16384, Ml + (size_t)c * 16384,
                Wf + (size_t)c * 4096);
}

// ---------------------------------------------------------------------------
// mscan: in-block serial within-group matrix prefix scan with packed LDS
// staging of the B node. grid 32 (g = bid>>1, h = bid&1), 320 threads.
__global__ __launch_bounds__(320) void mscan(const f16* __restrict__ MhA,
                                             const f16* __restrict__ MlA,
                                             const float* __restrict__ WA,
                                             f16* __restrict__ MhB,
                                             f16* __restrict__ MlB,
                                             float* __restrict__ WB) {
  __shared__ f16 Ph[80 * LDK], Pl[80 * LDK];
  __shared__ f16 BstH[2][PKF], BstL[2][PKF];
  const int g = blockIdx.x >> 1, h = blockIdx.x & 1;
  const int tid = threadIdx.x;
  int src[5];
  pk_precompute<320, 5>(tid, src);
  const size_t n0 = (size_t)(16 * g);
  // prologue: stage node n0+1 into buf 1 (step j uses buf j&1)
  pk_stage<320, 5>(MhA + (n0 + 1) * 16384, MlA + (n0 + 1) * 16384,
                   BstH[1], BstL[1], src, tid);
  load_prev_to_P(MhA + n0 * 16384, MlA + n0 * 16384, WA + n0 * 4096, h, Ph, Pl);
  const int wv = tid >> 6;
  const int mt = (wv == 4) ? (8 + h) : slot2mt(h, wv);
#pragma unroll 1
  for (int j = 1; j <= 15; ++j) {
    const size_t nd = n0 + j;
    const int cur = j & 1;
    const bool more = (j < 15);
    chain_step_pk(BstH[cur], BstL[cur], WA + nd * 4096, Ph, Pl, wv, mt,
                  more ? MhA + (nd + 1) * 16384 : nullptr,
                  more ? MlA + (nd + 1) * 16384 : nullptr,
                  BstH[cur ^ 1], BstL[cur ^ 1], src, tid);
    chain_copyout(Ph, Pl, h, MhB + nd * 16384, MlB + nd * 16384,
                  WB + nd * 4096);
  }
}

// ---------------------------------------------------------------------------
// gscan: serial Horner state scan over group totals (set B nodes 16t+15) with
// packed LDS staging. grid 32 (g = bid>>1, h = bid&1), 256 threads.
__global__ __launch_bounds__(256) void gscan(const f16* __restrict__ MhB,
                                             const f16* __restrict__ MlB,
                                             const float* __restrict__ WB,
                                             float* __restrict__ Ef) {
  __shared__ f16 Sh[16 * LDK], Sl[16 * LDK];
  __shared__ f16 GstH[2][PKF], GstL[2][PKF];
  const int g = blockIdx.x >> 1, h = blockIdx.x & 1;
  const int tid = threadIdx.x;
  int src[6];
  pk_precompute<256, 6>(tid, src);
  for (int t = tid; t < 16 * LDK; t += 256) { Sh[t] = (f16)0.f; Sl[t] = (f16)0.f; }
  if (g > 0)
    pk_stage<256, 6>(MhB + (size_t)15 * 16384, MlB + (size_t)15 * 16384,
                     GstH[0], GstL[0], src, tid);
  __syncthreads();  // zero-init visible + staged node 0 drained
#pragma unroll 1
  for (int t = 0; t < g; ++t) {
    const size_t nd = (size_t)(16 * t + 15);
    const size_t nn = (size_t)(16 * (t + 1) + 15);
    const int cur = t & 1;
    const bool more = (t + 1 < g);
    state_step_pk(GstH[cur], GstL[cur], WB + nd * 4096, Sh, Sl, h,
                  more ? MhB + nn * 16384 : nullptr,
                  more ? MlB + nn * 16384 : nullptr,
                  GstH[cur ^ 1], GstL[cur ^ 1], src, tid);
  }
  for (int t = tid; t < 2048; t += 256) {
    const int row = t & 15, n = t >> 4;
    Ef[(size_t)g * 4096 + n * 32 + h * 16 + row] =
        (float)Sh[row * LDK + n] + (float)Sl[row * LDK + n];
  }
}

// ---------------------------------------------------------------------------
// K3 h-split: grid 512 (c = bid>>1, h = bid&1), 320 thr, 16 batch rows each.
__global__ __launch_bounds__(320) void k3h(const float* __restrict__ A,
                                           const float* __restrict__ x,
                                           const float* __restrict__ Bv,
                                           const f16* __restrict__ MhA,
                                           const f16* __restrict__ MlA,
                                           const float* __restrict__ WA,
                                           const f16* __restrict__ MhB,
                                           const f16* __restrict__ MlB,
                                           const float* __restrict__ WB,
                                           const float* __restrict__ Ef,
                                           float* __restrict__ out) {
  __shared__ f16 Sh[16 * LDK], Sl[16 * LDK];
  __shared__ float Ast[9216];
  const int tid = threadIdx.x;
  const int c = blockIdx.x >> 1, h = blockIdx.x & 1;
  const int g = c >> 4, j = c & 15;
  int soff[8];
  compute_soff(tid, soff);
  issue_A(A + (size_t)(4 * c) * 16384, Ast, soff, tid);
  const float* Ew = Ef + (size_t)g * 4096;
  for (int tt = tid; tt < 2048; tt += 320) {
    const int row = tt & 15, n = tt >> 4;
    const float v = Ew[n * 32 + h * 16 + row];
    const f16 hh = (f16)v;
    Sh[row * LDK + n] = hh;
    Sl[row * LDK + n] = (f16)(v - (float)hh);
  }
  __syncthreads();
  if (j > 0) {
    const int nd = c - 1, jp = j - 1;
    const bool inA = (jp == 0);
    const f16* mh = (inA ? MhA : MhB) + (size_t)nd * 16384;
    const f16* ml = (inA ? MlA : MlB) + (size_t)nd * 16384;
    const float* w = (inA ? WA : WB) + (size_t)nd * 4096;
    state_step_h_b16(mh, ml, w, Sh, Sl, h);
  }
#pragma unroll 1
  for (int t4 = 0; t4 < 4; ++t4) {
    const int l = 4 * c + t4;
    const float* Anext = (t4 < 3) ? A + (size_t)(l + 1) * 16384 : nullptr;
    state_step_h_staged(A + (size_t)l * 16384, Anext, x + l * 32, Bv + l * 128,
                        Sh, Sl, out + (size_t)l * 4096, h, Ast, soff);
  }
}

// ---------------------------------------------------------------------------
extern "C" void kernel_launch(void* const* d_in, const int* in_sizes, int n_in,
                              void* d_out, int out_size, void* d_ws, size_t ws_size,
                              hipStream_t stream) {
  const float* x  = (const float*)d_in[0];  // (1024, 32)
  const float* A  = (const float*)d_in[1];  // (1024, 128, 128) lower-triangular
  const float* Bv = (const float*)d_in[2];  // (1024, 128)
  float* out = (float*)d_out;               // (1024, 32, 128)

  // set A: chunk units (k1 output)
  f16* MhA = (f16*)d_ws;                    // 256*16384 f16
  f16* MlA = MhA + 256 * 16384;
  float* WA = (float*)(MlA + 256 * 16384);  // 256*4096 f32
  // set B: within-group prefixes j>=1 (mscan output)
  f16* MhB = (f16*)(WA + 256 * 4096);
  f16* MlB = MhB + 256 * 16384;
  float* WB = (float*)(MlB + 256 * 16384);
  // entry states (f32)
  float* Ef = WB + 256 * 4096;              // 16*4096 f32; total ~42.2 MB

  k1_chunks<<<512, 320, 0, stream>>>(A, x, Bv, MhA, MlA, WA);
  mscan<<<32, 320, 0, stream>>>(MhA, MlA, WA, MhB, MlB, WB);
  gscan<<<32, 256, 0, stream>>>(MhB, MlB, WB, Ef);
  k3h<<<512, 320, 0, stream>>>(A, x, Bv, MhA, MlA, WA, MhB, MlB, WB, Ef, out);
}

// Round 7
// 252.806 us; speedup vs baseline: 2.0412x; 1.1557x over previous
//
#include <hip/hip_runtime.h>

// HiPPO-LegS scan — round 13: mscan LDS-pipe diet.
//  * mscan -> mscan_s: 64 blocks x 192 thr (per (g,h): 2 blocks {slots01+w} /
//    {slots23}); wave-private P rows -> ONE barrier/step; stage issued at
//    step START (full-step cover before its vmcnt drain); epilogue writes
//    prefix DIRECTLY to global (f16x4/float4) -- copyout LDS pass deleted;
//    odd-mt waves write explicit zero-tiles (nt=mt-1) to match old coverage.
//  * gscan: stage issued at step start + W loads hoisted pre-MFMA.
//  * k1 / k3h unchanged.
// Pipeline: k1(512) -> mscan_s(64) -> gscan(32) -> k3h(512). 4 launches.

#define LDK 136   // f16 k-stride of LDS state rows
#define PKF 11264 // f16 per packed triangular matrix (22528 B)

using f16 = _Float16;
typedef __attribute__((ext_vector_type(8))) f16 f16x8;
typedef __attribute__((ext_vector_type(4))) f16 f16x4;
typedef __attribute__((ext_vector_type(4))) float f32x4;

__device__ __forceinline__ f32x4 mfma3(f16x8 ah, f16x8 al, f16x8 bh, f16x8 bl,
                                       f32x4 c) {
  c = __builtin_amdgcn_mfma_f32_16x16x32_f16(ah, bh, c, 0, 0, 0);
  c = __builtin_amdgcn_mfma_f32_16x16x32_f16(ah, bl, c, 0, 0, 0);
  c = __builtin_amdgcn_mfma_f32_16x16x32_f16(al, bh, c, 0, 0, 0);
  return c;
}

__device__ __forceinline__ void split8(const float* v, f16x8& h, f16x8& l) {
#pragma unroll
  for (int j = 0; j < 8; ++j) {
    const float x = v[j];
    const f16 hh = (f16)x;
    h[j] = hh;
    l[j] = (f16)(x - (float)hh);
  }
}

// global m-tile owned by (h, slot): h=0 -> {0,7,1,6}, h=1 -> {2,5,3,4}
__device__ __forceinline__ int slot2mt(int h, int slot) {
  if (h == 0) return (slot & 1) ? 7 - (slot >> 1) : (slot >> 1);
  return (slot & 1) ? 5 - (slot >> 1) : 2 + (slot >> 1);
}

__device__ __forceinline__ void gload_lds16(const float* g, float* l) {
  __builtin_amdgcn_global_load_lds(
      (const __attribute__((address_space(1))) unsigned int*)g,
      (__attribute__((address_space(3))) unsigned int*)l, 16, 0, 0);
}

// ---------------------------------------------------------------------------
// Packed triangular matrix staging (f16). Bands of 32 rows; chunks(16B)/row
// padded to {4,8,16,16}; chunk-in-row XOR-swizzled by (ri & (cc-1)) —
// bijective per band. 1408 chunks = PKF f16 = 22528 B per matrix.
// f16 band bases {0,1024,3072,7168}; chunk bases {0,128,384,896}.

__device__ __forceinline__ int pk_src_off(int m) {  // global f16 offset of chunk m
  int b, local, ccm1, sh;
  if (m < 128)      { b = 0; local = m;       ccm1 = 3;  sh = 2; }
  else if (m < 384) { b = 1; local = m - 128; ccm1 = 7;  sh = 3; }
  else if (m < 896) { b = 2; local = m - 384; ccm1 = 15; sh = 4; }
  else              { b = 3; local = m - 896; ccm1 = 15; sh = 4; }
  const int ri = local >> sh, cp = local & ccm1;
  const int c = cp ^ (ri & ccm1);  // source chunk held in LDS slot cp
  return (b * 32 + ri) * 128 + c * 8;
}

// read source chunk j0 (= kt*4+q) of row nt*16+lr from a packed matrix
__device__ __forceinline__ void read_pk(const f16* __restrict__ Bs, int nt,
                                        int lr, int j0, f16x8& v) {
  const int b = nt >> 1;
  const int ri = ((nt & 1) << 4) + lr;
  const int ccm1 = (b == 0) ? 3 : (b == 1) ? 7 : 15;
  const int fb = (b == 0) ? 0 : (b == 1) ? 1024 : (b == 2) ? 3072 : 7168;
  const int c = j0 ^ (ri & ccm1);
  v = *(const f16x8*)(Bs + fb + ri * ((ccm1 + 1) * 8) + c * 8);
}

template <int NT, int IT>
__device__ __forceinline__ void pk_precompute(int tid, int (&src)[IT]) {
#pragma unroll
  for (int it = 0; it < IT; ++it) {
    const int m = tid + it * NT;
    src[it] = (m < 1408) ? pk_src_off(m) : 0;
  }
}

template <int NT, int IT>
__device__ __forceinline__ void pk_stage(const f16* __restrict__ gMh,
                                         const f16* __restrict__ gMl,
                                         f16* __restrict__ dH,
                                         f16* __restrict__ dL,
                                         const int (&src)[IT], int tid) {
#pragma unroll
  for (int it = 0; it < IT; ++it) {
    const int m = tid + it * NT;
    if (m < 1408) {
      gload_lds16((const float*)(gMh + src[it]), (float*)(dH + m * 8));
      gload_lds16((const float*)(gMl + src[it]), (float*)(dL + m * 8));
    }
  }
}

// ---------------------------------------------------------------------------
// Staged-A layout for k1/k3h (f32, LDS, 9216 floats = 36 KB) — unchanged.
__device__ __forceinline__ void compute_soff(int tid, int (&soff)[8]) {
#pragma unroll
  for (int it = 0; it < 8; ++it) {
    const int m = tid + it * 320;
    if (m < 2304) {
      const int kt = (m >= 768) + (m >= 1536) + (m >= 2048);
      const int local = m - ((kt >= 1) * 768 + (kt >= 2) * 768 + (kt >= 3) * 512);
      const int rp = local >> 3, c = local & 7;
      const int r = rp + 32 + (kt >= 2) * 32 + (kt >= 3) * 32;
      soff[it] = r * 128 + kt * 32 + ((c ^ (rp & 7)) << 2);
    } else {
      soff[it] = 0;
    }
  }
}

__device__ __forceinline__ void issue_A(const float* __restrict__ Al,
                                        float* __restrict__ Ast,
                                        const int (&soff)[8], int tid) {
#pragma unroll
  for (int it = 0; it < 8; ++it) {
    if (it < 7 || tid < 64)
      gload_lds16(Al + soff[it], Ast + (tid + it * 320) * 4);
  }
}

__device__ __forceinline__ void read_staged(const float* __restrict__ Ast,
                                            int nt, int kt, int lr, int q,
                                            f16x8& ch, f16x8& cl) {
  const int rp = nt * 16 + lr - (32 + (kt >= 2) * 32 + (kt >= 3) * 32);
  const float* pb =
      Ast + ((kt >= 1) * 3072 + (kt >= 2) * 3072 + (kt >= 3) * 2048) + rp * 32;
  float raw[8];
  *(float4*)&raw[0] = *(const float4*)(pb + (((2 * q + 0) ^ (rp & 7)) << 2));
  *(float4*)&raw[4] = *(const float4*)(pb + (((2 * q + 1) ^ (rp & 7)) << 2));
  split8(raw, ch, cl);
}

// ---------------------------------------------------------------------------
// chain_step_k1: B operand from staged f32 LDS (nt>=2) + direct regs (nt<2).
__device__ __forceinline__ void chain_step_k1(const float* __restrict__ Acur,
                                              const float* __restrict__ Anext,
                                              const float* __restrict__ x32,
                                              const float* __restrict__ Bvl,
                                              f16* __restrict__ Ph,
                                              f16* __restrict__ Pl,
                                              float* __restrict__ Ast,
                                              const int (&soff)[8],
                                              int wv, int mt) {
  const int tid = threadIdx.x;
  const int lane = tid & 63, lr = lane & 15, q = lane >> 4;
  const bool wrow = (mt >= 8);
  const int ktA0 = wrow ? 0 : (mt >> 1);
  f16x8 ah[4], al[4];
#pragma unroll
  for (int kt = 0; kt < 4; ++kt) {
    if (kt >= ktA0) {
      const int off = (wv * 16 + lr) * LDK + kt * 32 + q * 8;
      ah[kt] = *(const f16x8*)(Ph + off);
      al[kt] = *(const f16x8*)(Pl + off);
    }
  }
  const bool need0 = wrow || mt == 0;
  const bool need1 = wrow || mt <= 1;
  float dir0[8], dir1[8];
  if (need0) {
    const float* p = Acur + lr * 128 + q * 8;
    *(float4*)&dir0[0] = *(const float4*)p;
    *(float4*)&dir0[4] = *(const float4*)(p + 4);
  }
  if (need1) {
    const float* p = Acur + (16 + lr) * 128 + q * 8;
    *(float4*)&dir1[0] = *(const float4*)p;
    *(float4*)&dir1[4] = *(const float4*)(p + 4);
  }
  f32x4 acc[8];
#pragma unroll
  for (int nt = 0; nt < 8; ++nt) acc[nt] = (f32x4){0.f, 0.f, 0.f, 0.f};
#pragma unroll
  for (int nt = 2; nt < 8; ++nt) {
    if (wrow || nt >= mt) {
#pragma unroll
      for (int kt = 0; kt < 4; ++kt) {
        if (kt >= ktA0 && kt <= (nt >> 1)) {
          f16x8 ch, cl;
          read_staged(Ast, nt, kt, lr, q, ch, cl);
          acc[nt] = mfma3(ah[kt], al[kt], ch, cl, acc[nt]);
        }
      }
    }
  }
  if (need0) {
    f16x8 ch, cl;
    split8(dir0, ch, cl);
    acc[0] = mfma3(ah[0], al[0], ch, cl, acc[0]);
  }
  if (need1) {
    f16x8 ch, cl;
    split8(dir1, ch, cl);
    acc[1] = mfma3(ah[0], al[0], ch, cl, acc[1]);
  }
  __syncthreads();
  if (Anext) issue_A(Anext, Ast, soff, tid);
#pragma unroll
  for (int nt = 0; nt < 8; ++nt) {
    if (!(wrow || nt >= mt)) continue;
    float v[4] = {acc[nt][0], acc[nt][1], acc[nt][2], acc[nt][3]};
    if (wrow) {
      const int b0 = (mt - 8) * 16 + q * 4;
      const float4 x4 = *(const float4*)(x32 + b0);
      const float bn = Bvl[nt * 16 + lr];
      v[0] += bn * x4.x; v[1] += bn * x4.y; v[2] += bn * x4.z; v[3] += bn * x4.w;
    }
#pragma unroll
    for (int r = 0; r < 4; ++r) {
      const int o = (wv * 16 + q * 4 + r) * LDK + nt * 16 + lr;
      const f16 hh = (f16)v[r];
      Ph[o] = hh;
      Pl[o] = (f16)(v[r] - (float)hh);
    }
  }
  __syncthreads();
}

// copy P' out as PLAIN M (f16 hi/lo) + w (f32 [n][32]); triangular-gated. (k1)
__device__ __forceinline__ void chain_copyout(const f16* __restrict__ Ph,
                                              const f16* __restrict__ Pl, int h,
                                              f16* __restrict__ oMh,
                                              f16* __restrict__ oMl,
                                              float* __restrict__ oW) {
  const int tid = threadIdx.x;
  for (int t = tid; t < 1024; t += 320) {
    const int i = t >> 3;
    const int slot = (t >> 1) & 3;
    const int half = t & 1;
    const int mtg = slot2mt(h, slot);
    const int y0 = mtg * 16 + half * 8;
    if ((y0 >> 5) > (i >> 5)) continue;  // zero tile: skip store
    f16x8 hv, lv;
#pragma unroll
    for (int e = 0; e < 8; ++e) {
      hv[e] = Ph[(slot * 16 + half * 8 + e) * LDK + i];
      lv[e] = Pl[(slot * 16 + half * 8 + e) * LDK + i];
    }
    *(f16x8*)(oMh + i * 128 + y0) = hv;
    *(f16x8*)(oMl + i * 128 + y0) = lv;
  }
  for (int t = tid; t < 512; t += 320) {
    const int n = t >> 2, b4 = (t & 3) * 4;
    float4 o;
    float* po = (float*)&o;
#pragma unroll
    for (int e = 0; e < 4; ++e)
      po[e] = (float)Ph[(64 + b4 + e) * LDK + n] + (float)Pl[(64 + b4 + e) * LDK + n];
    *(float4*)(oW + n * 32 + h * 16 + b4) = o;
  }
}

// ---------------------------------------------------------------------------
// state_step_h_b16: 16-row state <- state * B^T (+w add), B from global. (k3h)
__device__ __forceinline__ void state_step_h_b16(const f16* __restrict__ Bh16,
                                                 const f16* __restrict__ Bl16,
                                                 const float* __restrict__ aux0,
                                                 f16* __restrict__ Sh,
                                                 f16* __restrict__ Sl, int h) {
  const int tid = threadIdx.x;
  const int wv4 = tid >> 6;
  const bool act = (wv4 < 4);
  const int wv = wv4 & 3;
  const int lane = tid & 63, lr = lane & 15, q = lane >> 4;
  const int nts[2] = {wv, 7 - wv};
  const int ktAmax = (7 - wv) >> 1;
  f16x8 ah[4], al[4];
  f16x8 bh[2][4], bl[2][4];
  f32x4 acc[2];
  if (act) {
#pragma unroll
    for (int kt = 0; kt < 4; ++kt)
      if (kt <= ktAmax) {
        const int off = lr * LDK + kt * 32 + q * 8;
        ah[kt] = *(const f16x8*)(Sh + off);
        al[kt] = *(const f16x8*)(Sl + off);
      }
#pragma unroll
    for (int ni = 0; ni < 2; ++ni) {
      const int nt = nts[ni];
#pragma unroll
      for (int kt = 0; kt < 4; ++kt)
        if (kt <= (nt >> 1)) {
          const int o = (nt * 16 + lr) * 128 + kt * 32 + q * 8;
          bh[ni][kt] = *(const f16x8*)(Bh16 + o);
          bl[ni][kt] = *(const f16x8*)(Bl16 + o);
        }
    }
#pragma unroll
    for (int ni = 0; ni < 2; ++ni) acc[ni] = (f32x4){0.f, 0.f, 0.f, 0.f};
#pragma unroll
    for (int ni = 0; ni < 2; ++ni) {
      const int nt = nts[ni];
#pragma unroll
      for (int kt = 0; kt < 4; ++kt)
        if (kt <= (nt >> 1))
          acc[ni] = mfma3(ah[kt], al[kt], bh[ni][kt], bl[ni][kt], acc[ni]);
    }
  }
  __syncthreads();
  if (act) {
#pragma unroll
    for (int ni = 0; ni < 2; ++ni) {
      const int nt = nts[ni];
      float v[4] = {acc[ni][0], acc[ni][1], acc[ni][2], acc[ni][3]};
      const int bq = q * 4;
      const float4 w4 = *(const float4*)(aux0 + (nt * 16 + lr) * 32 + h * 16 + bq);
      v[0] += w4.x; v[1] += w4.y; v[2] += w4.z; v[3] += w4.w;
#pragma unroll
      for (int r = 0; r < 4; ++r) {
        const int o = (bq + r) * LDK + nt * 16 + lr;
        const f16 hh = (f16)v[r];
        Sh[o] = hh;
        Sl[o] = (f16)(v[r] - (float)hh);
      }
    }
  }
  __syncthreads();
}

// state_step_h_staged: k3h replay step (f32 staged A) — unchanged.
__device__ __forceinline__ void state_step_h_staged(
    const float* __restrict__ Acur, const float* __restrict__ Anext,
    const float* __restrict__ x32, const float* __restrict__ Bvl,
    f16* __restrict__ Sh, f16* __restrict__ Sl, float* __restrict__ outp,
    int h, float* __restrict__ Ast, const int (&soff)[8]) {
  const int tid = threadIdx.x;
  const int wv4 = tid >> 6;
  const bool act = (wv4 < 4);
  const int wv = wv4 & 3;
  const int lane = tid & 63, lr = lane & 15, q = lane >> 4;
  const int ntL = wv, ntH = 7 - wv;
  f32x4 accL = (f32x4){0.f, 0.f, 0.f, 0.f}, accH = accL;
  if (act) {
    const int ktAmax = ntH >> 1;
    f16x8 ah[4], al[4];
#pragma unroll
    for (int kt = 0; kt < 4; ++kt)
      if (kt <= ktAmax) {
        const int off = lr * LDK + kt * 32 + q * 8;
        ah[kt] = *(const f16x8*)(Sh + off);
        al[kt] = *(const f16x8*)(Sl + off);
      }
    float dir[8];
    if (wv < 2) {
      const float* p = Acur + (ntL * 16 + lr) * 128 + q * 8;
      *(float4*)&dir[0] = *(const float4*)p;
      *(float4*)&dir[4] = *(const float4*)(p + 4);
    }
#pragma unroll
    for (int kt = 0; kt < 4; ++kt) {
      if (kt <= (ntH >> 1)) {
        f16x8 ch, cl;
        read_staged(Ast, ntH, kt, lr, q, ch, cl);
        accH = mfma3(ah[kt], al[kt], ch, cl, accH);
      }
    }
    if (wv >= 2) {
#pragma unroll
      for (int kt = 0; kt < 4; ++kt) {
        if (kt <= (ntL >> 1)) {
          f16x8 ch, cl;
          read_staged(Ast, ntL, kt, lr, q, ch, cl);
          accL = mfma3(ah[kt], al[kt], ch, cl, accL);
        }
      }
    } else {
      f16x8 ch, cl;
      split8(dir, ch, cl);
      accL = mfma3(ah[0], al[0], ch, cl, accL);
    }
  }
  __syncthreads();
  if (Anext) issue_A(Anext, Ast, soff, tid);
  if (act) {
#pragma unroll
    for (int ni = 0; ni < 2; ++ni) {
      const int nt = (ni == 0) ? ntL : ntH;
      const f32x4 a = (ni == 0) ? accL : accH;
      float v[4] = {a[0], a[1], a[2], a[3]};
      const int bq = q * 4;
      const float4 x4 = *(const float4*)(x32 + h * 16 + bq);
      const float bn = Bvl[nt * 16 + lr];
      v[0] += bn * x4.x; v[1] += bn * x4.y; v[2] += bn * x4.z; v[3] += bn * x4.w;
      if (outp) {
#pragma unroll
        for (int r = 0; r < 4; ++r)
          outp[(h * 16 + bq + r) * 128 + nt * 16 + lr] = v[r];
      }
#pragma unroll
      for (int r = 0; r < 4; ++r) {
        const int o = (bq + r) * LDK + nt * 16 + lr;
        const f16 hh = (f16)v[r];
        Sh[o] = hh;
        Sl[o] = (f16)(v[r] - (float)hh);
      }
    }
  }
  __syncthreads();
}

// ---------------------------------------------------------------------------
// K1: chunk units. grid 512 (c = bid>>1, h = bid&1), 320 threads. writes set A.
__global__ __launch_bounds__(320) void k1_chunks(const float* __restrict__ A,
                                                 const float* __restrict__ x,
                                                 const float* __restrict__ Bv,
                                                 f16* __restrict__ Mh,
                                                 f16* __restrict__ Ml,
                                                 float* __restrict__ Wf) {
  __shared__ f16 Ph[80 * LDK], Pl[80 * LDK];
  __shared__ float Ast[9216];
  const int tid = threadIdx.x;
  const int c = blockIdx.x >> 1, h = blockIdx.x & 1;
  const int l0 = 4 * c;
  int soff[8];
  compute_soff(tid, soff);
  issue_A(A + (size_t)(l0 + 1) * 16384, Ast, soff, tid);
  const float* A0 = A + (size_t)l0 * 16384;
  for (int t = tid; t < 2048; t += 320) {
    const int k = t >> 4, u = t & 15;
    const int slot = u >> 2, fo = (u & 3) * 4;
    const int mtg = slot2mt(h, slot);
    const int y = mtg * 16 + fo;
    float vv[4];
    if ((y >> 5) <= (k >> 5)) {
      const float4 v = *(const float4*)(A0 + k * 128 + y);
      vv[0] = v.x; vv[1] = v.y; vv[2] = v.z; vv[3] = v.w;
    } else {
      vv[0] = vv[1] = vv[2] = vv[3] = 0.f;
    }
#pragma unroll
    for (int e = 0; e < 4; ++e) {
      const f16 hh = (f16)vv[e];
      Ph[(slot * 16 + fo + e) * LDK + k] = hh;
      Pl[(slot * 16 + fo + e) * LDK + k] = (f16)(vv[e] - (float)hh);
    }
  }
  for (int t = tid; t < 512; t += 320) {
    const int b = t >> 5, n4 = (t & 31) * 4;
    const float xb = x[l0 * 32 + h * 16 + b];
#pragma unroll
    for (int e = 0; e < 4; ++e) {
      const float u = xb * Bv[l0 * 128 + n4 + e];
      const f16 hh = (f16)u;
      Ph[(64 + b) * LDK + n4 + e] = hh;
      Pl[(64 + b) * LDK + n4 + e] = (f16)(u - (float)hh);
    }
  }
  __syncthreads();
  const int wv = tid >> 6;
  const int mt = (wv == 4) ? (8 + h) : slot2mt(h, wv);
  chain_step_k1(A + (size_t)(l0 + 1) * 16384, A + (size_t)(l0 + 2) * 16384,
                x + (l0 + 1) * 32, Bv + (l0 + 1) * 128, Ph, Pl, Ast, soff, wv, mt);
  chain_step_k1(A + (size_t)(l0 + 2) * 16384, A + (size_t)(l0 + 3) * 16384,
                x + (l0 + 2) * 32, Bv + (l0 + 2) * 128, Ph, Pl, Ast, soff, wv, mt);
  chain_step_k1(A + (size_t)(l0 + 3) * 16384, nullptr,
                x + (l0 + 3) * 32, Bv + (l0 + 3) * 128, Ph, Pl, Ast, soff, wv, mt);
  chain_copyout(Ph, Pl, h, Mh + (size_t)c * 16384, Ml + (size_t)c * 16384,
                Wf + (size_t)c * 4096);
}

// ---------------------------------------------------------------------------
// mscan_s: within-group matrix prefix scan, wave-private P, fused writeback.
// grid 64 (bid -> g = bid>>2, h = (bid>>1)&1, half = bid&1), 192 threads.
// half 0: waves {slot0, slot1, w-rows}; half 1: waves {slot2, slot3, idle}.
// One barrier per step; stage issued at step start (full-step cover).
__global__ __launch_bounds__(192) void mscan_s(const f16* __restrict__ MhA,
                                               const f16* __restrict__ MlA,
                                               const float* __restrict__ WA,
                                               f16* __restrict__ MhB,
                                               f16* __restrict__ MlB,
                                               float* __restrict__ WB) {
  __shared__ f16 Ph[48 * LDK], Pl[48 * LDK];
  __shared__ f16 BstH[2][PKF], BstL[2][PKF];
  const int bid = blockIdx.x;
  const int g = bid >> 2, h = (bid >> 1) & 1, half = bid & 1;
  const int tid = threadIdx.x;
  const int wv = tid >> 6;
  const int lane = tid & 63, lr = lane & 15, q = lane >> 4;
  const bool isW = (half == 0 && wv == 2);
  const bool isM = (wv < 2);
  const int mt = isW ? (8 + h) : (isM ? slot2mt(h, half * 2 + wv) : 0);
  const int lw = wv * 16;                        // local P row base
  const int ktA0 = isW ? 0 : (mt >> 1);
  const size_t n0 = (size_t)(16 * g);

  int src[8];
  pk_precompute<192, 8>(tid, src);
  // prologue: stage node n0+1 -> buf[1]
  pk_stage<192, 8>(MhA + (n0 + 1) * 16384, MlA + (n0 + 1) * 16384,
                   BstH[1], BstL[1], src, tid);
  // wave-private P init from node n0 (triangular-gated / zero-filled)
  if (isM) {
    const f16* pMh = MhA + n0 * 16384;
    const f16* pMl = MlA + n0 * 16384;
#pragma unroll
    for (int it = 0; it < 4; ++it) {
      const int t = lane + it * 64;
      const int k = t >> 1, hk = t & 1;
      const int y0 = mt * 16 + hk * 8;
      f16x8 hv, lv;
      if ((y0 >> 5) <= (k >> 5)) {
        hv = *(const f16x8*)(pMh + k * 128 + y0);
        lv = *(const f16x8*)(pMl + k * 128 + y0);
      } else {
#pragma unroll
        for (int e = 0; e < 8; ++e) { hv[e] = (f16)0.f; lv[e] = (f16)0.f; }
      }
#pragma unroll
      for (int e = 0; e < 8; ++e) {
        Ph[(lw + hk * 8 + e) * LDK + k] = hv[e];
        Pl[(lw + hk * 8 + e) * LDK + k] = lv[e];
      }
    }
  } else if (isW) {
    const float* pW = WA + n0 * 4096;
#pragma unroll
    for (int it = 0; it < 8; ++it) {
      const int t = lane + it * 64;
      const int n = t >> 2, b4 = (t & 3) * 4;
      const float4 w4 = *(const float4*)(pW + n * 32 + h * 16 + b4);
      const float vv[4] = {w4.x, w4.y, w4.z, w4.w};
#pragma unroll
      for (int r = 0; r < 4; ++r) {
        const f16 hh = (f16)vv[r];
        Ph[(lw + b4 + r) * LDK + n] = hh;
        Pl[(lw + b4 + r) * LDK + n] = (f16)(vv[r] - (float)hh);
      }
    }
  }
  __syncthreads();  // stage(1) drained; enter loop

#pragma unroll 1
  for (int j = 1; j <= 15; ++j) {
    const size_t nd = n0 + j;
    const int cur = j & 1;
    // stage node j+1 at step START (buffer last read in step j-1 -> safe)
    if (j < 15)
      pk_stage<192, 8>(MhA + (nd + 1) * 16384, MlA + (nd + 1) * 16384,
                       BstH[cur ^ 1], BstL[cur ^ 1], src, tid);
    // W prefetch for this step's add (w-wave only; covered by MFMA)
    float4 w4s[8];
    if (isW) {
      const float* Wn = WA + nd * 4096;
#pragma unroll
      for (int nt = 0; nt < 8; ++nt)
        w4s[nt] = *(const float4*)(Wn + (nt * 16 + lr) * 32 + h * 16 + q * 4);
    }
    // fragments from own P rows (wave-private; same-wave LDS ordering)
    f16x8 ah[4], al[4];
    if (isM || isW) {
#pragma unroll
      for (int kt = 0; kt < 4; ++kt)
        if (kt >= ktA0) {
          const int off = (lw + lr) * LDK + kt * 32 + q * 8;
          ah[kt] = *(const f16x8*)(Ph + off);
          al[kt] = *(const f16x8*)(Pl + off);
        }
    }
    f32x4 acc[8];
#pragma unroll
    for (int nt = 0; nt < 8; ++nt) acc[nt] = (f32x4){0.f, 0.f, 0.f, 0.f};
    if (isM || isW) {
      const int ntF = isW ? 0 : mt;
#pragma unroll
      for (int nt = 0; nt < 8; ++nt) {
        if (nt >= ntF) {
#pragma unroll
          for (int kt = 0; kt < 4; ++kt) {
            if (kt >= ktA0 && kt <= (nt >> 1)) {
              f16x8 bh, bl;
              const int j0 = kt * 4 + q;
              read_pk(BstH[cur], nt, lr, j0, bh);
              read_pk(BstL[cur], nt, lr, j0, bl);
              acc[nt] = mfma3(ah[kt], al[kt], bh, bl, acc[nt]);
            }
          }
        }
      }
    }
    // epilogue: update own P rows + fused global writeback of prefix nd
    if (isM) {
      f16* oMh = MhB + nd * 16384;
      f16* oMl = MlB + nd * 16384;
      if (mt & 1) {  // zero tile (k-tile mt-1): readers expect zeros
        const int k = (mt - 1) * 16 + lr;
        const f16x4 z = {(f16)0.f, (f16)0.f, (f16)0.f, (f16)0.f};
        *(f16x4*)(oMh + k * 128 + mt * 16 + q * 4) = z;
        *(f16x4*)(oMl + k * 128 + mt * 16 + q * 4) = z;
      }
#pragma unroll
      for (int nt = 0; nt < 8; ++nt) {
        if (nt < mt) continue;
        f16x4 hv4, lv4;
#pragma unroll
        for (int r = 0; r < 4; ++r) {
          const float v = acc[nt][r];
          const f16 hh = (f16)v;
          const f16 ll = (f16)(v - (float)hh);
          hv4[r] = hh;
          lv4[r] = ll;
          Ph[(lw + q * 4 + r) * LDK + nt * 16 + lr] = hh;
          Pl[(lw + q * 4 + r) * LDK + nt * 16 + lr] = ll;
        }
        const int k = nt * 16 + lr;
        *(f16x4*)(oMh + k * 128 + mt * 16 + q * 4) = hv4;
        *(f16x4*)(oMl + k * 128 + mt * 16 + q * 4) = lv4;
      }
    } else if (isW) {
      float* oW = WB + nd * 4096;
#pragma unroll
      for (int nt = 0; nt < 8; ++nt) {
        float v[4];
#pragma unroll
        for (int r = 0; r < 4; ++r) v[r] = acc[nt][r];
        v[0] += w4s[nt].x; v[1] += w4s[nt].y; v[2] += w4s[nt].z; v[3] += w4s[nt].w;
#pragma unroll
        for (int r = 0; r < 4; ++r) {
          const f16 hh = (f16)v[r];
          Ph[(lw + q * 4 + r) * LDK + nt * 16 + lr] = hh;
          Pl[(lw + q * 4 + r) * LDK + nt * 16 + lr] = (f16)(v[r] - (float)hh);
        }
        const float4 o = {v[0], v[1], v[2], v[3]};
        *(float4*)(oW + (nt * 16 + lr) * 32 + h * 16 + q * 4) = o;
      }
    }
    __syncthreads();  // single barrier: drains stage(j+1); buf ready for j+1
  }
}

// ---------------------------------------------------------------------------
// gscan: serial Horner state scan over group totals (set B nodes 16t+15).
// grid 32 (g = bid>>1, h = bid&1), 256 threads. Stage issued at step START;
// W loads hoisted pre-MFMA. Writes entry states Ef[g] (g=0 -> zeros).
__global__ __launch_bounds__(256) void gscan(const f16* __restrict__ MhB,
                                             const f16* __restrict__ MlB,
                                             const float* __restrict__ WB,
                                             float* __restrict__ Ef) {
  __shared__ f16 Sh[16 * LDK], Sl[16 * LDK];
  __shared__ f16 GstH[2][PKF], GstL[2][PKF];
  const int g = blockIdx.x >> 1, h = blockIdx.x & 1;
  const int tid = threadIdx.x;
  int src[6];
  pk_precompute<256, 6>(tid, src);
  for (int t = tid; t < 16 * LDK; t += 256) { Sh[t] = (f16)0.f; Sl[t] = (f16)0.f; }
  if (g > 0)
    pk_stage<256, 6>(MhB + (size_t)15 * 16384, MlB + (size_t)15 * 16384,
                     GstH[0], GstL[0], src, tid);
  __syncthreads();  // zero-init visible + staged node 0 drained
  const int wv = (tid >> 6) & 3;
  const int lane = tid & 63, lr = lane & 15, q = lane >> 4;
  const int nts[2] = {wv, 7 - wv};
  const int ktAmax = (7 - wv) >> 1;
#pragma unroll 1
  for (int t = 0; t < g; ++t) {
    const size_t nd = (size_t)(16 * t + 15);
    const int cur = t & 1;
    if (t + 1 < g) {
      const size_t nn = (size_t)(16 * (t + 1) + 15);
      pk_stage<256, 6>(MhB + nn * 16384, MlB + nn * 16384,
                       GstH[cur ^ 1], GstL[cur ^ 1], src, tid);
    }
    const float* aux0 = WB + nd * 4096;
    float4 w4s[2];
#pragma unroll
    for (int ni = 0; ni < 2; ++ni)
      w4s[ni] = *(const float4*)(aux0 + (nts[ni] * 16 + lr) * 32 + h * 16 + q * 4);
    f16x8 ah[4], al[4];
#pragma unroll
    for (int kt = 0; kt < 4; ++kt)
      if (kt <= ktAmax) {
        const int off = lr * LDK + kt * 32 + q * 8;
        ah[kt] = *(const f16x8*)(Sh + off);
        al[kt] = *(const f16x8*)(Sl + off);
      }
    f32x4 acc[2];
#pragma unroll
    for (int ni = 0; ni < 2; ++ni) acc[ni] = (f32x4){0.f, 0.f, 0.f, 0.f};
#pragma unroll
    for (int ni = 0; ni < 2; ++ni) {
      const int nt = nts[ni];
#pragma unroll
      for (int kt = 0; kt < 4; ++kt)
        if (kt <= (nt >> 1)) {
          f16x8 bh, bl;
          const int j0 = kt * 4 + q;
          read_pk(GstH[cur], nt, lr, j0, bh);
          read_pk(GstL[cur], nt, lr, j0, bl);
          acc[ni] = mfma3(ah[kt], al[kt], bh, bl, acc[ni]);
        }
    }
    __syncthreads();  // all S frag reads done
#pragma unroll
    for (int ni = 0; ni < 2; ++ni) {
      const int nt = nts[ni];
      float v[4] = {acc[ni][0], acc[ni][1], acc[ni][2], acc[ni][3]};
      v[0] += w4s[ni].x; v[1] += w4s[ni].y; v[2] += w4s[ni].z; v[3] += w4s[ni].w;
#pragma unroll
      for (int r = 0; r < 4; ++r) {
        const int o = (q * 4 + r) * LDK + nt * 16 + lr;
        const f16 hh = (f16)v[r];
        Sh[o] = hh;
        Sl[o] = (f16)(v[r] - (float)hh);
      }
    }
    __syncthreads();  // epilogue S writes visible
  }
  for (int t = tid; t < 2048; t += 256) {
    const int row = t & 15, n = t >> 4;
    Ef[(size_t)g * 4096 + n * 32 + h * 16 + row] =
        (float)Sh[row * LDK + n] + (float)Sl[row * LDK + n];
  }
}

// ---------------------------------------------------------------------------
// K3 h-split: grid 512 (c = bid>>1, h = bid&1), 320 thr, 16 batch rows each.
__global__ __launch_bounds__(320) void k3h(const float* __restrict__ A,
                                           const float* __restrict__ x,
                                           const float* __restrict__ Bv,
                                           const f16* __restrict__ MhA,
                                           const f16* __restrict__ MlA,
                                           const float* __restrict__ WA,
                                           const f16* __restrict__ MhB,
                                           const f16* __restrict__ MlB,
                                           const float* __restrict__ WB,
                                           const float* __restrict__ Ef,
                                           float* __restrict__ out) {
  __shared__ f16 Sh[16 * LDK], Sl[16 * LDK];
  __shared__ float Ast[9216];
  const int tid = threadIdx.x;
  const int c = blockIdx.x >> 1, h = blockIdx.x & 1;
  const int g = c >> 4, j = c & 15;
  int soff[8];
  compute_soff(tid, soff);
  issue_A(A + (size_t)(4 * c) * 16384, Ast, soff, tid);
  const float* Ew = Ef + (size_t)g * 4096;
  for (int tt = tid; tt < 2048; tt += 320) {
    const int row = tt & 15, n = tt >> 4;
    const float v = Ew[n * 32 + h * 16 + row];
    const f16 hh = (f16)v;
    Sh[row * LDK + n] = hh;
    Sl[row * LDK + n] = (f16)(v - (float)hh);
  }
  __syncthreads();
  if (j > 0) {
    const int nd = c - 1, jp = j - 1;
    const bool inA = (jp == 0);
    const f16* mh = (inA ? MhA : MhB) + (size_t)nd * 16384;
    const f16* ml = (inA ? MlA : MlB) + (size_t)nd * 16384;
    const float* w = (inA ? WA : WB) + (size_t)nd * 4096;
    state_step_h_b16(mh, ml, w, Sh, Sl, h);
  }
#pragma unroll 1
  for (int t4 = 0; t4 < 4; ++t4) {
    const int l = 4 * c + t4;
    const float* Anext = (t4 < 3) ? A + (size_t)(l + 1) * 16384 : nullptr;
    state_step_h_staged(A + (size_t)l * 16384, Anext, x + l * 32, Bv + l * 128,
                        Sh, Sl, out + (size_t)l * 4096, h, Ast, soff);
  }
}

// ---------------------------------------------------------------------------
extern "C" void kernel_launch(void* const* d_in, const int* in_sizes, int n_in,
                              void* d_out, int out_size, void* d_ws, size_t ws_size,
                              hipStream_t stream) {
  const float* x  = (const float*)d_in[0];  // (1024, 32)
  const float* A  = (const float*)d_in[1];  // (1024, 128, 128) lower-triangular
  const float* Bv = (const float*)d_in[2];  // (1024, 128)
  float* out = (float*)d_out;               // (1024, 32, 128)

  // set A: chunk units (k1 output)
  f16* MhA = (f16*)d_ws;                    // 256*16384 f16
  f16* MlA = MhA + 256 * 16384;
  float* WA = (float*)(MlA + 256 * 16384);  // 256*4096 f32
  // set B: within-group prefixes j>=1 (mscan_s output)
  f16* MhB = (f16*)(WA + 256 * 4096);
  f16* MlB = MhB + 256 * 16384;
  float* WB = (float*)(MlB + 256 * 16384);
  // entry states (f32)
  float* Ef = WB + 256 * 4096;              // 16*4096 f32; total ~42.2 MB

  k1_chunks<<<512, 320, 0, stream>>>(A, x, Bv, MhA, MlA, WA);
  mscan_s<<<64, 192, 0, stream>>>(MhA, MlA, WA, MhB, MlB, WB);
  gscan<<<32, 256, 0, stream>>>(MhB, MlB, WB, Ef);
  k3h<<<512, 320, 0, stream>>>(A, x, Bv, MhA, MlA, WA, MhB, MlB, WB, Ef, out);
}

// Round 8
// 243.447 us; speedup vs baseline: 2.1197x; 1.0384x over previous
//
#include <hip/hip_runtime.h>

// HiPPO-LegS scan — round 14: XCD co-location grid remap (no semantic change).
//  * Round-13 counters: mscan FETCH 28.5 MB vs ~11.5 MB unique -> the 4
//    sibling blocks per group stage IDENTICAL node data but land on different
//    XCDs (private L2s) under round-robin bid%8 placement -> HBM-class
//    streaming (~4500 cy/step) exposed at the per-step vmcnt(0) drain.
//  * Fix: remap grids so siblings differ by bid multiples of 8:
//      k1 / k3h : c = bid&255, h = bid>>8   (h-siblings share A-chunk via L2)
//      mscan_s  : g = bid&15,  unit = bid>>4 (4 stage-siblings share one L2)
//      gscan    : g = bid&15,  h = bid>>4
//  * Everything else identical to round 13.
// Pipeline: k1(512) -> mscan_s(64) -> gscan(32) -> k3h(512). 4 launches.

#define LDK 136   // f16 k-stride of LDS state rows
#define PKF 11264 // f16 per packed triangular matrix (22528 B)

using f16 = _Float16;
typedef __attribute__((ext_vector_type(8))) f16 f16x8;
typedef __attribute__((ext_vector_type(4))) f16 f16x4;
typedef __attribute__((ext_vector_type(4))) float f32x4;

__device__ __forceinline__ f32x4 mfma3(f16x8 ah, f16x8 al, f16x8 bh, f16x8 bl,
                                       f32x4 c) {
  c = __builtin_amdgcn_mfma_f32_16x16x32_f16(ah, bh, c, 0, 0, 0);
  c = __builtin_amdgcn_mfma_f32_16x16x32_f16(ah, bl, c, 0, 0, 0);
  c = __builtin_amdgcn_mfma_f32_16x16x32_f16(al, bh, c, 0, 0, 0);
  return c;
}

__device__ __forceinline__ void split8(const float* v, f16x8& h, f16x8& l) {
#pragma unroll
  for (int j = 0; j < 8; ++j) {
    const float x = v[j];
    const f16 hh = (f16)x;
    h[j] = hh;
    l[j] = (f16)(x - (float)hh);
  }
}

// global m-tile owned by (h, slot): h=0 -> {0,7,1,6}, h=1 -> {2,5,3,4}
__device__ __forceinline__ int slot2mt(int h, int slot) {
  if (h == 0) return (slot & 1) ? 7 - (slot >> 1) : (slot >> 1);
  return (slot & 1) ? 5 - (slot >> 1) : 2 + (slot >> 1);
}

__device__ __forceinline__ void gload_lds16(const float* g, float* l) {
  __builtin_amdgcn_global_load_lds(
      (const __attribute__((address_space(1))) unsigned int*)g,
      (__attribute__((address_space(3))) unsigned int*)l, 16, 0, 0);
}

// ---------------------------------------------------------------------------
// Packed triangular matrix staging (f16). Bands of 32 rows; chunks(16B)/row
// padded to {4,8,16,16}; chunk-in-row XOR-swizzled by (ri & (cc-1)) —
// bijective per band. 1408 chunks = PKF f16 = 22528 B per matrix.
// f16 band bases {0,1024,3072,7168}; chunk bases {0,128,384,896}.

__device__ __forceinline__ int pk_src_off(int m) {  // global f16 offset of chunk m
  int b, local, ccm1, sh;
  if (m < 128)      { b = 0; local = m;       ccm1 = 3;  sh = 2; }
  else if (m < 384) { b = 1; local = m - 128; ccm1 = 7;  sh = 3; }
  else if (m < 896) { b = 2; local = m - 384; ccm1 = 15; sh = 4; }
  else              { b = 3; local = m - 896; ccm1 = 15; sh = 4; }
  const int ri = local >> sh, cp = local & ccm1;
  const int c = cp ^ (ri & ccm1);  // source chunk held in LDS slot cp
  return (b * 32 + ri) * 128 + c * 8;
}

// read source chunk j0 (= kt*4+q) of row nt*16+lr from a packed matrix
__device__ __forceinline__ void read_pk(const f16* __restrict__ Bs, int nt,
                                        int lr, int j0, f16x8& v) {
  const int b = nt >> 1;
  const int ri = ((nt & 1) << 4) + lr;
  const int ccm1 = (b == 0) ? 3 : (b == 1) ? 7 : 15;
  const int fb = (b == 0) ? 0 : (b == 1) ? 1024 : (b == 2) ? 3072 : 7168;
  const int c = j0 ^ (ri & ccm1);
  v = *(const f16x8*)(Bs + fb + ri * ((ccm1 + 1) * 8) + c * 8);
}

template <int NT, int IT>
__device__ __forceinline__ void pk_precompute(int tid, int (&src)[IT]) {
#pragma unroll
  for (int it = 0; it < IT; ++it) {
    const int m = tid + it * NT;
    src[it] = (m < 1408) ? pk_src_off(m) : 0;
  }
}

template <int NT, int IT>
__device__ __forceinline__ void pk_stage(const f16* __restrict__ gMh,
                                         const f16* __restrict__ gMl,
                                         f16* __restrict__ dH,
                                         f16* __restrict__ dL,
                                         const int (&src)[IT], int tid) {
#pragma unroll
  for (int it = 0; it < IT; ++it) {
    const int m = tid + it * NT;
    if (m < 1408) {
      gload_lds16((const float*)(gMh + src[it]), (float*)(dH + m * 8));
      gload_lds16((const float*)(gMl + src[it]), (float*)(dL + m * 8));
    }
  }
}

// ---------------------------------------------------------------------------
// Staged-A layout for k1/k3h (f32, LDS, 9216 floats = 36 KB) — unchanged.
__device__ __forceinline__ void compute_soff(int tid, int (&soff)[8]) {
#pragma unroll
  for (int it = 0; it < 8; ++it) {
    const int m = tid + it * 320;
    if (m < 2304) {
      const int kt = (m >= 768) + (m >= 1536) + (m >= 2048);
      const int local = m - ((kt >= 1) * 768 + (kt >= 2) * 768 + (kt >= 3) * 512);
      const int rp = local >> 3, c = local & 7;
      const int r = rp + 32 + (kt >= 2) * 32 + (kt >= 3) * 32;
      soff[it] = r * 128 + kt * 32 + ((c ^ (rp & 7)) << 2);
    } else {
      soff[it] = 0;
    }
  }
}

__device__ __forceinline__ void issue_A(const float* __restrict__ Al,
                                        float* __restrict__ Ast,
                                        const int (&soff)[8], int tid) {
#pragma unroll
  for (int it = 0; it < 8; ++it) {
    if (it < 7 || tid < 64)
      gload_lds16(Al + soff[it], Ast + (tid + it * 320) * 4);
  }
}

__device__ __forceinline__ void read_staged(const float* __restrict__ Ast,
                                            int nt, int kt, int lr, int q,
                                            f16x8& ch, f16x8& cl) {
  const int rp = nt * 16 + lr - (32 + (kt >= 2) * 32 + (kt >= 3) * 32);
  const float* pb =
      Ast + ((kt >= 1) * 3072 + (kt >= 2) * 3072 + (kt >= 3) * 2048) + rp * 32;
  float raw[8];
  *(float4*)&raw[0] = *(const float4*)(pb + (((2 * q + 0) ^ (rp & 7)) << 2));
  *(float4*)&raw[4] = *(const float4*)(pb + (((2 * q + 1) ^ (rp & 7)) << 2));
  split8(raw, ch, cl);
}

// ---------------------------------------------------------------------------
// chain_step_k1: B operand from staged f32 LDS (nt>=2) + direct regs (nt<2).
__device__ __forceinline__ void chain_step_k1(const float* __restrict__ Acur,
                                              const float* __restrict__ Anext,
                                              const float* __restrict__ x32,
                                              const float* __restrict__ Bvl,
                                              f16* __restrict__ Ph,
                                              f16* __restrict__ Pl,
                                              float* __restrict__ Ast,
                                              const int (&soff)[8],
                                              int wv, int mt) {
  const int tid = threadIdx.x;
  const int lane = tid & 63, lr = lane & 15, q = lane >> 4;
  const bool wrow = (mt >= 8);
  const int ktA0 = wrow ? 0 : (mt >> 1);
  f16x8 ah[4], al[4];
#pragma unroll
  for (int kt = 0; kt < 4; ++kt) {
    if (kt >= ktA0) {
      const int off = (wv * 16 + lr) * LDK + kt * 32 + q * 8;
      ah[kt] = *(const f16x8*)(Ph + off);
      al[kt] = *(const f16x8*)(Pl + off);
    }
  }
  const bool need0 = wrow || mt == 0;
  const bool need1 = wrow || mt <= 1;
  float dir0[8], dir1[8];
  if (need0) {
    const float* p = Acur + lr * 128 + q * 8;
    *(float4*)&dir0[0] = *(const float4*)p;
    *(float4*)&dir0[4] = *(const float4*)(p + 4);
  }
  if (need1) {
    const float* p = Acur + (16 + lr) * 128 + q * 8;
    *(float4*)&dir1[0] = *(const float4*)p;
    *(float4*)&dir1[4] = *(const float4*)(p + 4);
  }
  f32x4 acc[8];
#pragma unroll
  for (int nt = 0; nt < 8; ++nt) acc[nt] = (f32x4){0.f, 0.f, 0.f, 0.f};
#pragma unroll
  for (int nt = 2; nt < 8; ++nt) {
    if (wrow || nt >= mt) {
#pragma unroll
      for (int kt = 0; kt < 4; ++kt) {
        if (kt >= ktA0 && kt <= (nt >> 1)) {
          f16x8 ch, cl;
          read_staged(Ast, nt, kt, lr, q, ch, cl);
          acc[nt] = mfma3(ah[kt], al[kt], ch, cl, acc[nt]);
        }
      }
    }
  }
  if (need0) {
    f16x8 ch, cl;
    split8(dir0, ch, cl);
    acc[0] = mfma3(ah[0], al[0], ch, cl, acc[0]);
  }
  if (need1) {
    f16x8 ch, cl;
    split8(dir1, ch, cl);
    acc[1] = mfma3(ah[0], al[0], ch, cl, acc[1]);
  }
  __syncthreads();
  if (Anext) issue_A(Anext, Ast, soff, tid);
#pragma unroll
  for (int nt = 0; nt < 8; ++nt) {
    if (!(wrow || nt >= mt)) continue;
    float v[4] = {acc[nt][0], acc[nt][1], acc[nt][2], acc[nt][3]};
    if (wrow) {
      const int b0 = (mt - 8) * 16 + q * 4;
      const float4 x4 = *(const float4*)(x32 + b0);
      const float bn = Bvl[nt * 16 + lr];
      v[0] += bn * x4.x; v[1] += bn * x4.y; v[2] += bn * x4.z; v[3] += bn * x4.w;
    }
#pragma unroll
    for (int r = 0; r < 4; ++r) {
      const int o = (wv * 16 + q * 4 + r) * LDK + nt * 16 + lr;
      const f16 hh = (f16)v[r];
      Ph[o] = hh;
      Pl[o] = (f16)(v[r] - (float)hh);
    }
  }
  __syncthreads();
}

// copy P' out as PLAIN M (f16 hi/lo) + w (f32 [n][32]); triangular-gated. (k1)
__device__ __forceinline__ void chain_copyout(const f16* __restrict__ Ph,
                                              const f16* __restrict__ Pl, int h,
                                              f16* __restrict__ oMh,
                                              f16* __restrict__ oMl,
                                              float* __restrict__ oW) {
  const int tid = threadIdx.x;
  for (int t = tid; t < 1024; t += 320) {
    const int i = t >> 3;
    const int slot = (t >> 1) & 3;
    const int half = t & 1;
    const int mtg = slot2mt(h, slot);
    const int y0 = mtg * 16 + half * 8;
    if ((y0 >> 5) > (i >> 5)) continue;  // zero tile: skip store
    f16x8 hv, lv;
#pragma unroll
    for (int e = 0; e < 8; ++e) {
      hv[e] = Ph[(slot * 16 + half * 8 + e) * LDK + i];
      lv[e] = Pl[(slot * 16 + half * 8 + e) * LDK + i];
    }
    *(f16x8*)(oMh + i * 128 + y0) = hv;
    *(f16x8*)(oMl + i * 128 + y0) = lv;
  }
  for (int t = tid; t < 512; t += 320) {
    const int n = t >> 2, b4 = (t & 3) * 4;
    float4 o;
    float* po = (float*)&o;
#pragma unroll
    for (int e = 0; e < 4; ++e)
      po[e] = (float)Ph[(64 + b4 + e) * LDK + n] + (float)Pl[(64 + b4 + e) * LDK + n];
    *(float4*)(oW + n * 32 + h * 16 + b4) = o;
  }
}

// ---------------------------------------------------------------------------
// state_step_h_b16: 16-row state <- state * B^T (+w add), B from global. (k3h)
__device__ __forceinline__ void state_step_h_b16(const f16* __restrict__ Bh16,
                                                 const f16* __restrict__ Bl16,
                                                 const float* __restrict__ aux0,
                                                 f16* __restrict__ Sh,
                                                 f16* __restrict__ Sl, int h) {
  const int tid = threadIdx.x;
  const int wv4 = tid >> 6;
  const bool act = (wv4 < 4);
  const int wv = wv4 & 3;
  const int lane = tid & 63, lr = lane & 15, q = lane >> 4;
  const int nts[2] = {wv, 7 - wv};
  const int ktAmax = (7 - wv) >> 1;
  f16x8 ah[4], al[4];
  f16x8 bh[2][4], bl[2][4];
  f32x4 acc[2];
  if (act) {
#pragma unroll
    for (int kt = 0; kt < 4; ++kt)
      if (kt <= ktAmax) {
        const int off = lr * LDK + kt * 32 + q * 8;
        ah[kt] = *(const f16x8*)(Sh + off);
        al[kt] = *(const f16x8*)(Sl + off);
      }
#pragma unroll
    for (int ni = 0; ni < 2; ++ni) {
      const int nt = nts[ni];
#pragma unroll
      for (int kt = 0; kt < 4; ++kt)
        if (kt <= (nt >> 1)) {
          const int o = (nt * 16 + lr) * 128 + kt * 32 + q * 8;
          bh[ni][kt] = *(const f16x8*)(Bh16 + o);
          bl[ni][kt] = *(const f16x8*)(Bl16 + o);
        }
    }
#pragma unroll
    for (int ni = 0; ni < 2; ++ni) acc[ni] = (f32x4){0.f, 0.f, 0.f, 0.f};
#pragma unroll
    for (int ni = 0; ni < 2; ++ni) {
      const int nt = nts[ni];
#pragma unroll
      for (int kt = 0; kt < 4; ++kt)
        if (kt <= (nt >> 1))
          acc[ni] = mfma3(ah[kt], al[kt], bh[ni][kt], bl[ni][kt], acc[ni]);
    }
  }
  __syncthreads();
  if (act) {
#pragma unroll
    for (int ni = 0; ni < 2; ++ni) {
      const int nt = nts[ni];
      float v[4] = {acc[ni][0], acc[ni][1], acc[ni][2], acc[ni][3]};
      const int bq = q * 4;
      const float4 w4 = *(const float4*)(aux0 + (nt * 16 + lr) * 32 + h * 16 + bq);
      v[0] += w4.x; v[1] += w4.y; v[2] += w4.z; v[3] += w4.w;
#pragma unroll
      for (int r = 0; r < 4; ++r) {
        const int o = (bq + r) * LDK + nt * 16 + lr;
        const f16 hh = (f16)v[r];
        Sh[o] = hh;
        Sl[o] = (f16)(v[r] - (float)hh);
      }
    }
  }
  __syncthreads();
}

// state_step_h_staged: k3h replay step (f32 staged A) — unchanged.
__device__ __forceinline__ void state_step_h_staged(
    const float* __restrict__ Acur, const float* __restrict__ Anext,
    const float* __restrict__ x32, const float* __restrict__ Bvl,
    f16* __restrict__ Sh, f16* __restrict__ Sl, float* __restrict__ outp,
    int h, float* __restrict__ Ast, const int (&soff)[8]) {
  const int tid = threadIdx.x;
  const int wv4 = tid >> 6;
  const bool act = (wv4 < 4);
  const int wv = wv4 & 3;
  const int lane = tid & 63, lr = lane & 15, q = lane >> 4;
  const int ntL = wv, ntH = 7 - wv;
  f32x4 accL = (f32x4){0.f, 0.f, 0.f, 0.f}, accH = accL;
  if (act) {
    const int ktAmax = ntH >> 1;
    f16x8 ah[4], al[4];
#pragma unroll
    for (int kt = 0; kt < 4; ++kt)
      if (kt <= ktAmax) {
        const int off = lr * LDK + kt * 32 + q * 8;
        ah[kt] = *(const f16x8*)(Sh + off);
        al[kt] = *(const f16x8*)(Sl + off);
      }
    float dir[8];
    if (wv < 2) {
      const float* p = Acur + (ntL * 16 + lr) * 128 + q * 8;
      *(float4*)&dir[0] = *(const float4*)p;
      *(float4*)&dir[4] = *(const float4*)(p + 4);
    }
#pragma unroll
    for (int kt = 0; kt < 4; ++kt) {
      if (kt <= (ntH >> 1)) {
        f16x8 ch, cl;
        read_staged(Ast, ntH, kt, lr, q, ch, cl);
        accH = mfma3(ah[kt], al[kt], ch, cl, accH);
      }
    }
    if (wv >= 2) {
#pragma unroll
      for (int kt = 0; kt < 4; ++kt) {
        if (kt <= (ntL >> 1)) {
          f16x8 ch, cl;
          read_staged(Ast, ntL, kt, lr, q, ch, cl);
          accL = mfma3(ah[kt], al[kt], ch, cl, accL);
        }
      }
    } else {
      f16x8 ch, cl;
      split8(dir, ch, cl);
      accL = mfma3(ah[0], al[0], ch, cl, accL);
    }
  }
  __syncthreads();
  if (Anext) issue_A(Anext, Ast, soff, tid);
  if (act) {
#pragma unroll
    for (int ni = 0; ni < 2; ++ni) {
      const int nt = (ni == 0) ? ntL : ntH;
      const f32x4 a = (ni == 0) ? accL : accH;
      float v[4] = {a[0], a[1], a[2], a[3]};
      const int bq = q * 4;
      const float4 x4 = *(const float4*)(x32 + h * 16 + bq);
      const float bn = Bvl[nt * 16 + lr];
      v[0] += bn * x4.x; v[1] += bn * x4.y; v[2] += bn * x4.z; v[3] += bn * x4.w;
      if (outp) {
#pragma unroll
        for (int r = 0; r < 4; ++r)
          outp[(h * 16 + bq + r) * 128 + nt * 16 + lr] = v[r];
      }
#pragma unroll
      for (int r = 0; r < 4; ++r) {
        const int o = (bq + r) * LDK + nt * 16 + lr;
        const f16 hh = (f16)v[r];
        Sh[o] = hh;
        Sl[o] = (f16)(v[r] - (float)hh);
      }
    }
  }
  __syncthreads();
}

// ---------------------------------------------------------------------------
// K1: chunk units. grid 512; XCD remap: c = bid&255, h = bid>>8 (h-siblings
// share an XCD L2 for their common A-chunk reads). 320 threads. writes set A.
__global__ __launch_bounds__(320) void k1_chunks(const float* __restrict__ A,
                                                 const float* __restrict__ x,
                                                 const float* __restrict__ Bv,
                                                 f16* __restrict__ Mh,
                                                 f16* __restrict__ Ml,
                                                 float* __restrict__ Wf) {
  __shared__ f16 Ph[80 * LDK], Pl[80 * LDK];
  __shared__ float Ast[9216];
  const int tid = threadIdx.x;
  const int c = blockIdx.x & 255, h = blockIdx.x >> 8;
  const int l0 = 4 * c;
  int soff[8];
  compute_soff(tid, soff);
  issue_A(A + (size_t)(l0 + 1) * 16384, Ast, soff, tid);
  const float* A0 = A + (size_t)l0 * 16384;
  for (int t = tid; t < 2048; t += 320) {
    const int k = t >> 4, u = t & 15;
    const int slot = u >> 2, fo = (u & 3) * 4;
    const int mtg = slot2mt(h, slot);
    const int y = mtg * 16 + fo;
    float vv[4];
    if ((y >> 5) <= (k >> 5)) {
      const float4 v = *(const float4*)(A0 + k * 128 + y);
      vv[0] = v.x; vv[1] = v.y; vv[2] = v.z; vv[3] = v.w;
    } else {
      vv[0] = vv[1] = vv[2] = vv[3] = 0.f;
    }
#pragma unroll
    for (int e = 0; e < 4; ++e) {
      const f16 hh = (f16)vv[e];
      Ph[(slot * 16 + fo + e) * LDK + k] = hh;
      Pl[(slot * 16 + fo + e) * LDK + k] = (f16)(vv[e] - (float)hh);
    }
  }
  for (int t = tid; t < 512; t += 320) {
    const int b = t >> 5, n4 = (t & 31) * 4;
    const float xb = x[l0 * 32 + h * 16 + b];
#pragma unroll
    for (int e = 0; e < 4; ++e) {
      const float u = xb * Bv[l0 * 128 + n4 + e];
      const f16 hh = (f16)u;
      Ph[(64 + b) * LDK + n4 + e] = hh;
      Pl[(64 + b) * LDK + n4 + e] = (f16)(u - (float)hh);
    }
  }
  __syncthreads();
  const int wv = tid >> 6;
  const int mt = (wv == 4) ? (8 + h) : slot2mt(h, wv);
  chain_step_k1(A + (size_t)(l0 + 1) * 16384, A + (size_t)(l0 + 2) * 16384,
                x + (l0 + 1) * 32, Bv + (l0 + 1) * 128, Ph, Pl, Ast, soff, wv, mt);
  chain_step_k1(A + (size_t)(l0 + 2) * 16384, A + (size_t)(l0 + 3) * 16384,
                x + (l0 + 2) * 32, Bv + (l0 + 2) * 128, Ph, Pl, Ast, soff, wv, mt);
  chain_step_k1(A + (size_t)(l0 + 3) * 16384, nullptr,
                x + (l0 + 3) * 32, Bv + (l0 + 3) * 128, Ph, Pl, Ast, soff, wv, mt);
  chain_copyout(Ph, Pl, h, Mh + (size_t)c * 16384, Ml + (size_t)c * 16384,
                Wf + (size_t)c * 4096);
}

// ---------------------------------------------------------------------------
// mscan_s: within-group matrix prefix scan, wave-private P, fused writeback.
// grid 64; XCD remap: g = bid&15, unit = bid>>4 (4 stage-siblings of a group
// at bid, +16, +32, +48 -> same XCD -> shared L2 for identical staged nodes).
// unit: half = unit&1, h = unit>>1. 192 threads.
// half 0: waves {slot0, slot1, w-rows}; half 1: waves {slot2, slot3, idle}.
__global__ __launch_bounds__(192) void mscan_s(const f16* __restrict__ MhA,
                                               const f16* __restrict__ MlA,
                                               const float* __restrict__ WA,
                                               f16* __restrict__ MhB,
                                               f16* __restrict__ MlB,
                                               float* __restrict__ WB) {
  __shared__ f16 Ph[48 * LDK], Pl[48 * LDK];
  __shared__ f16 BstH[2][PKF], BstL[2][PKF];
  const int bid = blockIdx.x;
  const int g = bid & 15, unit = bid >> 4;
  const int h = unit >> 1, half = unit & 1;
  const int tid = threadIdx.x;
  const int wv = tid >> 6;
  const int lane = tid & 63, lr = lane & 15, q = lane >> 4;
  const bool isW = (half == 0 && wv == 2);
  const bool isM = (wv < 2);
  const int mt = isW ? (8 + h) : (isM ? slot2mt(h, half * 2 + wv) : 0);
  const int lw = wv * 16;                        // local P row base
  const int ktA0 = isW ? 0 : (mt >> 1);
  const size_t n0 = (size_t)(16 * g);

  int src[8];
  pk_precompute<192, 8>(tid, src);
  // prologue: stage node n0+1 -> buf[1]
  pk_stage<192, 8>(MhA + (n0 + 1) * 16384, MlA + (n0 + 1) * 16384,
                   BstH[1], BstL[1], src, tid);
  // wave-private P init from node n0 (triangular-gated / zero-filled)
  if (isM) {
    const f16* pMh = MhA + n0 * 16384;
    const f16* pMl = MlA + n0 * 16384;
#pragma unroll
    for (int it = 0; it < 4; ++it) {
      const int t = lane + it * 64;
      const int k = t >> 1, hk = t & 1;
      const int y0 = mt * 16 + hk * 8;
      f16x8 hv, lv;
      if ((y0 >> 5) <= (k >> 5)) {
        hv = *(const f16x8*)(pMh + k * 128 + y0);
        lv = *(const f16x8*)(pMl + k * 128 + y0);
      } else {
#pragma unroll
        for (int e = 0; e < 8; ++e) { hv[e] = (f16)0.f; lv[e] = (f16)0.f; }
      }
#pragma unroll
      for (int e = 0; e < 8; ++e) {
        Ph[(lw + hk * 8 + e) * LDK + k] = hv[e];
        Pl[(lw + hk * 8 + e) * LDK + k] = lv[e];
      }
    }
  } else if (isW) {
    const float* pW = WA + n0 * 4096;
#pragma unroll
    for (int it = 0; it < 8; ++it) {
      const int t = lane + it * 64;
      const int n = t >> 2, b4 = (t & 3) * 4;
      const float4 w4 = *(const float4*)(pW + n * 32 + h * 16 + b4);
      const float vv[4] = {w4.x, w4.y, w4.z, w4.w};
#pragma unroll
      for (int r = 0; r < 4; ++r) {
        const f16 hh = (f16)vv[r];
        Ph[(lw + b4 + r) * LDK + n] = hh;
        Pl[(lw + b4 + r) * LDK + n] = (f16)(vv[r] - (float)hh);
      }
    }
  }
  __syncthreads();  // stage(1) drained; enter loop

#pragma unroll 1
  for (int j = 1; j <= 15; ++j) {
    const size_t nd = n0 + j;
    const int cur = j & 1;
    // stage node j+1 at step START (buffer last read in step j-1 -> safe)
    if (j < 15)
      pk_stage<192, 8>(MhA + (nd + 1) * 16384, MlA + (nd + 1) * 16384,
                       BstH[cur ^ 1], BstL[cur ^ 1], src, tid);
    // W prefetch for this step's add (w-wave only; covered by MFMA)
    float4 w4s[8];
    if (isW) {
      const float* Wn = WA + nd * 4096;
#pragma unroll
      for (int nt = 0; nt < 8; ++nt)
        w4s[nt] = *(const float4*)(Wn + (nt * 16 + lr) * 32 + h * 16 + q * 4);
    }
    // fragments from own P rows (wave-private; same-wave LDS ordering)
    f16x8 ah[4], al[4];
    if (isM || isW) {
#pragma unroll
      for (int kt = 0; kt < 4; ++kt)
        if (kt >= ktA0) {
          const int off = (lw + lr) * LDK + kt * 32 + q * 8;
          ah[kt] = *(const f16x8*)(Ph + off);
          al[kt] = *(const f16x8*)(Pl + off);
        }
    }
    f32x4 acc[8];
#pragma unroll
    for (int nt = 0; nt < 8; ++nt) acc[nt] = (f32x4){0.f, 0.f, 0.f, 0.f};
    if (isM || isW) {
      const int ntF = isW ? 0 : mt;
#pragma unroll
      for (int nt = 0; nt < 8; ++nt) {
        if (nt >= ntF) {
#pragma unroll
          for (int kt = 0; kt < 4; ++kt) {
            if (kt >= ktA0 && kt <= (nt >> 1)) {
              f16x8 bh, bl;
              const int j0 = kt * 4 + q;
              read_pk(BstH[cur], nt, lr, j0, bh);
              read_pk(BstL[cur], nt, lr, j0, bl);
              acc[nt] = mfma3(ah[kt], al[kt], bh, bl, acc[nt]);
            }
          }
        }
      }
    }
    // epilogue: update own P rows + fused global writeback of prefix nd
    if (isM) {
      f16* oMh = MhB + nd * 16384;
      f16* oMl = MlB + nd * 16384;
      if (mt & 1) {  // zero tile (k-tile mt-1): readers expect zeros
        const int k = (mt - 1) * 16 + lr;
        const f16x4 z = {(f16)0.f, (f16)0.f, (f16)0.f, (f16)0.f};
        *(f16x4*)(oMh + k * 128 + mt * 16 + q * 4) = z;
        *(f16x4*)(oMl + k * 128 + mt * 16 + q * 4) = z;
      }
#pragma unroll
      for (int nt = 0; nt < 8; ++nt) {
        if (nt < mt) continue;
        f16x4 hv4, lv4;
#pragma unroll
        for (int r = 0; r < 4; ++r) {
          const float v = acc[nt][r];
          const f16 hh = (f16)v;
          const f16 ll = (f16)(v - (float)hh);
          hv4[r] = hh;
          lv4[r] = ll;
          Ph[(lw + q * 4 + r) * LDK + nt * 16 + lr] = hh;
          Pl[(lw + q * 4 + r) * LDK + nt * 16 + lr] = ll;
        }
        const int k = nt * 16 + lr;
        *(f16x4*)(oMh + k * 128 + mt * 16 + q * 4) = hv4;
        *(f16x4*)(oMl + k * 128 + mt * 16 + q * 4) = lv4;
      }
    } else if (isW) {
      float* oW = WB + nd * 4096;
#pragma unroll
      for (int nt = 0; nt < 8; ++nt) {
        float v[4];
#pragma unroll
        for (int r = 0; r < 4; ++r) v[r] = acc[nt][r];
        v[0] += w4s[nt].x; v[1] += w4s[nt].y; v[2] += w4s[nt].z; v[3] += w4s[nt].w;
#pragma unroll
        for (int r = 0; r < 4; ++r) {
          const f16 hh = (f16)v[r];
          Ph[(lw + q * 4 + r) * LDK + nt * 16 + lr] = hh;
          Pl[(lw + q * 4 + r) * LDK + nt * 16 + lr] = (f16)(v[r] - (float)hh);
        }
        const float4 o = {v[0], v[1], v[2], v[3]};
        *(float4*)(oW + (nt * 16 + lr) * 32 + h * 16 + q * 4) = o;
      }
    }
    __syncthreads();  // single barrier: drains stage(j+1); buf ready for j+1
  }
}

// ---------------------------------------------------------------------------
// gscan: serial Horner state scan over group totals (set B nodes 16t+15).
// grid 32; XCD remap: g = bid&15, h = bid>>4 (h-siblings same XCD; g and g+8
// share an XCD for overlapping node-prefix reads). 256 threads.
__global__ __launch_bounds__(256) void gscan(const f16* __restrict__ MhB,
                                             const f16* __restrict__ MlB,
                                             const float* __restrict__ WB,
                                             float* __restrict__ Ef) {
  __shared__ f16 Sh[16 * LDK], Sl[16 * LDK];
  __shared__ f16 GstH[2][PKF], GstL[2][PKF];
  const int g = blockIdx.x & 15, h = blockIdx.x >> 4;
  const int tid = threadIdx.x;
  int src[6];
  pk_precompute<256, 6>(tid, src);
  for (int t = tid; t < 16 * LDK; t += 256) { Sh[t] = (f16)0.f; Sl[t] = (f16)0.f; }
  if (g > 0)
    pk_stage<256, 6>(MhB + (size_t)15 * 16384, MlB + (size_t)15 * 16384,
                     GstH[0], GstL[0], src, tid);
  __syncthreads();  // zero-init visible + staged node 0 drained
  const int wv = (tid >> 6) & 3;
  const int lane = tid & 63, lr = lane & 15, q = lane >> 4;
  const int nts[2] = {wv, 7 - wv};
  const int ktAmax = (7 - wv) >> 1;
#pragma unroll 1
  for (int t = 0; t < g; ++t) {
    const size_t nd = (size_t)(16 * t + 15);
    const int cur = t & 1;
    if (t + 1 < g) {
      const size_t nn = (size_t)(16 * (t + 1) + 15);
      pk_stage<256, 6>(MhB + nn * 16384, MlB + nn * 16384,
                       GstH[cur ^ 1], GstL[cur ^ 1], src, tid);
    }
    const float* aux0 = WB + nd * 4096;
    float4 w4s[2];
#pragma unroll
    for (int ni = 0; ni < 2; ++ni)
      w4s[ni] = *(const float4*)(aux0 + (nts[ni] * 16 + lr) * 32 + h * 16 + q * 4);
    f16x8 ah[4], al[4];
#pragma unroll
    for (int kt = 0; kt < 4; ++kt)
      if (kt <= ktAmax) {
        const int off = lr * LDK + kt * 32 + q * 8;
        ah[kt] = *(const f16x8*)(Sh + off);
        al[kt] = *(const f16x8*)(Sl + off);
      }
    f32x4 acc[2];
#pragma unroll
    for (int ni = 0; ni < 2; ++ni) acc[ni] = (f32x4){0.f, 0.f, 0.f, 0.f};
#pragma unroll
    for (int ni = 0; ni < 2; ++ni) {
      const int nt = nts[ni];
#pragma unroll
      for (int kt = 0; kt < 4; ++kt)
        if (kt <= (nt >> 1)) {
          f16x8 bh, bl;
          const int j0 = kt * 4 + q;
          read_pk(GstH[cur], nt, lr, j0, bh);
          read_pk(GstL[cur], nt, lr, j0, bl);
          acc[ni] = mfma3(ah[kt], al[kt], bh, bl, acc[ni]);
        }
    }
    __syncthreads();  // all S frag reads done
#pragma unroll
    for (int ni = 0; ni < 2; ++ni) {
      const int nt = nts[ni];
      float v[4] = {acc[ni][0], acc[ni][1], acc[ni][2], acc[ni][3]};
      v[0] += w4s[ni].x; v[1] += w4s[ni].y; v[2] += w4s[ni].z; v[3] += w4s[ni].w;
#pragma unroll
      for (int r = 0; r < 4; ++r) {
        const int o = (q * 4 + r) * LDK + nt * 16 + lr;
        const f16 hh = (f16)v[r];
        Sh[o] = hh;
        Sl[o] = (f16)(v[r] - (float)hh);
      }
    }
    __syncthreads();  // epilogue S writes visible
  }
  for (int t = tid; t < 2048; t += 256) {
    const int row = t & 15, n = t >> 4;
    Ef[(size_t)g * 4096 + n * 32 + h * 16 + row] =
        (float)Sh[row * LDK + n] + (float)Sl[row * LDK + n];
  }
}

// ---------------------------------------------------------------------------
// K3 h-split: grid 512; XCD remap: c = bid&255, h = bid>>8 (h-siblings share
// A-chunk + prefix-node reads via one L2). 320 thr, 16 batch rows each.
__global__ __launch_bounds__(320) void k3h(const float* __restrict__ A,
                                           const float* __restrict__ x,
                                           const float* __restrict__ Bv,
                                           const f16* __restrict__ MhA,
                                           const f16* __restrict__ MlA,
                                           const float* __restrict__ WA,
                                           const f16* __restrict__ MhB,
                                           const f16* __restrict__ MlB,
                                           const float* __restrict__ WB,
                                           const float* __restrict__ Ef,
                                           float* __restrict__ out) {
  __shared__ f16 Sh[16 * LDK], Sl[16 * LDK];
  __shared__ float Ast[9216];
  const int tid = threadIdx.x;
  const int c = blockIdx.x & 255, h = blockIdx.x >> 8;
  const int g = c >> 4, j = c & 15;
  int soff[8];
  compute_soff(tid, soff);
  issue_A(A + (size_t)(4 * c) * 16384, Ast, soff, tid);
  const float* Ew = Ef + (size_t)g * 4096;
  for (int tt = tid; tt < 2048; tt += 320) {
    const int row = tt & 15, n = tt >> 4;
    const float v = Ew[n * 32 + h * 16 + row];
    const f16 hh = (f16)v;
    Sh[row * LDK + n] = hh;
    Sl[row * LDK + n] = (f16)(v - (float)hh);
  }
  __syncthreads();
  if (j > 0) {
    const int nd = c - 1, jp = j - 1;
    const bool inA = (jp == 0);
    const f16* mh = (inA ? MhA : MhB) + (size_t)nd * 16384;
    const f16* ml = (inA ? MlA : MlB) + (size_t)nd * 16384;
    const float* w = (inA ? WA : WB) + (size_t)nd * 4096;
    state_step_h_b16(mh, ml, w, Sh, Sl, h);
  }
#pragma unroll 1
  for (int t4 = 0; t4 < 4; ++t4) {
    const int l = 4 * c + t4;
    const float* Anext = (t4 < 3) ? A + (size_t)(l + 1) * 16384 : nullptr;
    state_step_h_staged(A + (size_t)l * 16384, Anext, x + l * 32, Bv + l * 128,
                        Sh, Sl, out + (size_t)l * 4096, h, Ast, soff);
  }
}

// ---------------------------------------------------------------------------
extern "C" void kernel_launch(void* const* d_in, const int* in_sizes, int n_in,
                              void* d_out, int out_size, void* d_ws, size_t ws_size,
                              hipStream_t stream) {
  const float* x  = (const float*)d_in[0];  // (1024, 32)
  const float* A  = (const float*)d_in[1];  // (1024, 128, 128) lower-triangular
  const float* Bv = (const float*)d_in[2];  // (1024, 128)
  float* out = (float*)d_out;               // (1024, 32, 128)

  // set A: chunk units (k1 output)
  f16* MhA = (f16*)d_ws;                    // 256*16384 f16
  f16* MlA = MhA + 256 * 16384;
  float* WA = (float*)(MlA + 256 * 16384);  // 256*4096 f32
  // set B: within-group prefixes j>=1 (mscan_s output)
  f16* MhB = (f16*)(WA + 256 * 4096);
  f16* MlB = MhB + 256 * 16384;
  float* WB = (float*)(MlB + 256 * 16384);
  // entry states (f32)
  float* Ef = WB + 256 * 4096;              // 16*4096 f32; total ~42.2 MB

  k1_chunks<<<512, 320, 0, stream>>>(A, x, Bv, MhA, MlA, WA);
  mscan_s<<<64, 192, 0, stream>>>(MhA, MlA, WA, MhB, MlB, WB);
  gscan<<<32, 256, 0, stream>>>(MhB, MlB, WB, Ef);
  k3h<<<512, 320, 0, stream>>>(A, x, Bv, MhA, MlA, WA, MhB, MlB, WB, Ef, out);
}